// Round 1
// 263.914 us; speedup vs baseline: 1.0502x; 1.0502x over previous
//
#include <hip/hip_runtime.h>
#include <cstdint>
#include <cstddef>

typedef __bf16 bf16;
typedef __attribute__((ext_vector_type(8))) __bf16 bf16x8;
typedef __attribute__((ext_vector_type(4))) __bf16 bf16x4;
typedef __attribute__((ext_vector_type(4))) float f32x4;
typedef __attribute__((ext_vector_type(4))) short s16x4;

#define S_LEN   2048
#define WIN     512
#define NH_Q    16
#define NH_KV   4
#define HD_     128
#define NTOK    4096   // B * S

#if defined(__has_builtin)
#if __has_builtin(__builtin_amdgcn_mfma_f32_16x16x16bf16_1k)
#define HAVE_MFMA16 1
#endif
#endif
#ifndef HAVE_MFMA16
#define HAVE_MFMA16 0
#endif

// s_waitcnt immediates (gfx9 encoding: vm[3:0]=s[3:0], exp=s[6:4],
// lgkm=s[11:8], vm[5:4]=s[15:14]); non-waited fields all-ones.
#define WAIT_VM4   0x0F74  // vmcnt<=4
#define WAIT_VM2   0x0F72  // vmcnt<=2
#define WAIT_VM0   0x0F70  // vmcnt<=0
#define CFENCE() __asm__ __volatile__("" ::: "memory")

// async global->LDS, 16B per lane; LDS dest = wave-uniform base + lane*16
__device__ __forceinline__ void async_copy16(const void* g, void* l) {
  __builtin_amdgcn_global_load_lds(
      (const __attribute__((address_space(1))) void*)g,
      (__attribute__((address_space(3))) void*)l, 16, 0, 0);
}

// ---------------- fp32 -> bf16 convert, all 5 arrays in one launch ----------
__global__ __launch_bounds__(256)
void cvt_all(const float* __restrict__ hs, const float* __restrict__ wq,
             const float* __restrict__ wk, const float* __restrict__ wv,
             const float* __restrict__ wo, bf16* __restrict__ hsb,
             bf16* __restrict__ wqb, bf16* __restrict__ wkb,
             bf16* __restrict__ wvb, bf16* __restrict__ wob) {
  long i = ((long)blockIdx.x * 256 + threadIdx.x) * 4;  // < 18874368
  const float* in;
  bf16* out;
  if (i < 8388608)       { in = hs + i;            out = hsb + i; }
  else if (i < 12582912) { in = wq + (i - 8388608); out = wqb + (i - 8388608); }
  else if (i < 13631488) { in = wk + (i - 12582912); out = wkb + (i - 12582912); }
  else if (i < 14680064) { in = wv + (i - 13631488); out = wvb + (i - 13631488); }
  else                   { in = wo + (i - 14680064); out = wob + (i - 14680064); }
  float4 v = *(const float4*)in;
  bf16x4 t = {(bf16)v.x, (bf16)v.y, (bf16)v.z, (bf16)v.w};
  *(bf16x4*)out = t;
}

// ---------------- GEMM (barrier-style, R6): in-run CONTROL ------------------
// 128x128 tile, BK=32, dbuf, swizzled LDS (0 conflicts, R6-verified).
template <typename OutT>
__global__ __launch_bounds__(256)
void gemm_bt(const bf16* __restrict__ A, const bf16* __restrict__ W,
             OutT* __restrict__ C, int M, int N, int K) {
  __shared__ __align__(16) bf16 As[2][128 * 32];
  __shared__ __align__(16) bf16 Bs[2][128 * 32];
  const int tid  = threadIdx.x;
  const int wave = tid >> 6, lane = tid & 63;
  const int quad = lane >> 4, l16 = lane & 15;
  const int wm = wave >> 1, wn = wave & 1;
  const int m0 = blockIdx.y * 128, n0 = blockIdx.x * 128;
  const int lrow = lane >> 2;
  const int lcol = (((lane & 3) + ((lane >> 3) & 3)) & 3) * 8;  // swizzled src k
  const int gfrag = ((quad - ((l16 >> 1) & 3)) & 3) * 8;        // swizzled read k

  f32x4 acc[4][4];
#pragma unroll
  for (int i = 0; i < 4; ++i)
#pragma unroll
    for (int j = 0; j < 4; ++j) acc[i][j] = (f32x4){0.f, 0.f, 0.f, 0.f};

  auto stage = [&](int buf, int k0) {
#pragma unroll
    for (int it = 0; it < 2; ++it) {
      const int c   = it * 4 + wave;
      const int row = c * 16 + lrow;
      async_copy16(A + (size_t)(m0 + row) * K + k0 + lcol, &As[buf][c * 512]);
      async_copy16(W + (size_t)(n0 + row) * K + k0 + lcol, &Bs[buf][c * 512]);
    }
  };

  stage(0, 0);
  __syncthreads();
  for (int k0 = 0; k0 < K; k0 += 32) {
    const int cur = (k0 >> 5) & 1;
    if (k0 + 32 < K) stage(cur ^ 1, k0 + 32);
    bf16x8 af[4], bfr[4];
#pragma unroll
    for (int mt = 0; mt < 4; ++mt)
      af[mt] = *(const bf16x8*)&As[cur][(wm * 64 + mt * 16 + l16) * 32 + gfrag];
#pragma unroll
    for (int nt = 0; nt < 4; ++nt)
      bfr[nt] = *(const bf16x8*)&Bs[cur][(wn * 64 + nt * 16 + l16) * 32 + gfrag];
#pragma unroll
    for (int mt = 0; mt < 4; ++mt)
#pragma unroll
      for (int nt = 0; nt < 4; ++nt)
        acc[mt][nt] = __builtin_amdgcn_mfma_f32_16x16x32_bf16(
            af[mt], bfr[nt], acc[mt][nt], 0, 0, 0);
    __syncthreads();
  }
#pragma unroll
  for (int mt = 0; mt < 4; ++mt)
#pragma unroll
    for (int nt = 0; nt < 4; ++nt)
#pragma unroll
      for (int r = 0; r < 4; ++r) {
        const int row = m0 + wm * 64 + mt * 16 + quad * 4 + r;
        const int col = n0 + wn * 64 + nt * 16 + l16;
        C[(size_t)row * N + col] = (OutT)acc[mt][nt][r];
      }
}

// ---------------- fused QKV GEMM: 256x256 8-wave phase schedule -------------
// T2 st_16x32 swizzle (blocked 16x32 subtiles, byte^=((byte>>9)&1)<<5; LDS
// write is linear via global_load_lds, source col pre-swizzled, read addr
// swizzled -- rule 21 both-sides). T3/T4: 4 phases per K-tile, stage units
// issued in first-needed order (A0,B0,B1,A1) so every main-loop wait is
// counted vmcnt(4), never 0; drain 4->2->0 only in peeled last tile. Each
// wave's own vmcnt wait precedes s_barrier => barrier release collectively
// confirms all waves' LDS writes landed (race-free; stages always target the
// opposite double-buffer). T5: setprio around each 16-MFMA cluster. T1:
// bijective XCD swizzle over grid 192 = 8 XCD x 24.
__global__ __launch_bounds__(512, 2)
void gemm_qkv8(const bf16* __restrict__ A, const bf16* __restrict__ Wq,
               const bf16* __restrict__ Wk, const bf16* __restrict__ Wv,
               bf16* __restrict__ Qo, bf16* __restrict__ Ko,
               bf16* __restrict__ Vt) {
  __shared__ __align__(16) char smem[131072];  // A[2]:0/32K, B[2]:64K/96K
  const int tid  = threadIdx.x;
  const int wave = tid >> 6, lane = tid & 63;
  const int quad = lane >> 4, l16 = lane & 15;
  const int wm = wave >> 2, wn = wave & 3;     // 2x4 wave grid, 128x64 each

  // XCD-swizzled tile coords (grid 12 x 16 = 192 = 8 XCD x 24, bijective)
  const int flat = blockIdx.y * 12 + blockIdx.x;
  const int swz  = (flat & 7) * 24 + (flat >> 3);
  const int m0 = (swz / 12) * 256;
  const int n0 = (swz % 12) * 256;

  // swizzled within-subtile read byte offset (st_16x32)
  const int rdb = (l16 * 64 + quad * 16) ^ ((l16 & 8) << 2);

  // ---- stage source (pre-swizzled global col) + LDS dest, per unit ----
  const int srow = lane >> 2;
  const int scol = ((lane & 3) * 8) ^ ((lane >> 5) << 4);
  const bf16* asrc = A + (size_t)(m0 + srow) * 2048 + scol;
  const bf16* aptr[2][2];
  int adst[2][2];
#pragma unroll
  for (int mh = 0; mh < 2; ++mh)
#pragma unroll
    for (int j = 0; j < 2; ++j) {
      const int rb = j * 8 + mh * 4 + (wave >> 1);
      aptr[mh][j] = asrc + (size_t)rb * 16 * 2048 + (wave & 1) * 32;
      adst[mh][j] = (rb * 2 + (wave & 1)) << 10;
    }
  const bf16* bptr[2][2];
  int bdst[2][2];
#pragma unroll
  for (int nh = 0; nh < 2; ++nh)
#pragma unroll
    for (int j = 0; j < 2; ++j) {
      const int rb = j * 8 + (wave >> 2) * 4 + nh * 2 + ((wave >> 1) & 1);
      const int nrow = n0 + rb * 16 + srow;   // 16-row blocks never straddle
      const bf16* p = nrow < 2048 ? Wq + (size_t)nrow * 2048
                    : nrow < 2560 ? Wk + (size_t)(nrow - 2048) * 2048
                                  : Wv + (size_t)(nrow - 2560) * 2048;
      bptr[nh][j] = p + scol + (wave & 1) * 32;
      bdst[nh][j] = (rb * 2 + (wave & 1)) << 10;
    }

#define STAGE_A(mh, tt) do {                                        \
    char* _b = smem + ((tt) & 1) * 32768;                           \
    async_copy16(aptr[mh][0] + (tt) * 64, _b + adst[mh][0]);        \
    async_copy16(aptr[mh][1] + (tt) * 64, _b + adst[mh][1]);        \
  } while (0)
#define STAGE_B(nh, tt) do {                                        \
    char* _b = smem + 65536 + ((tt) & 1) * 32768;                   \
    async_copy16(bptr[nh][0] + (tt) * 64, _b + bdst[nh][0]);        \
    async_copy16(bptr[nh][1] + (tt) * 64, _b + bdst[nh][1]);        \
  } while (0)

  f32x4 acc[8][4];
#pragma unroll
  for (int i = 0; i < 8; ++i)
#pragma unroll
    for (int j = 0; j < 4; ++j) acc[i][j] = (f32x4){0.f, 0.f, 0.f, 0.f};

  bf16x8 afr[4][2];      // current mh quadrant's A frags (reused across nh)
  bf16x8 bfr[2][2][2];   // [nh][nt][ks] held across whole K-tile

  auto read_a = [&](const char* Ab, int mh) __attribute__((always_inline)) {
#pragma unroll
    for (int mt = 0; mt < 4; ++mt)
#pragma unroll
      for (int ks = 0; ks < 2; ++ks)
        afr[mt][ks] = *(const bf16x8*)(
            Ab + (((wm * 8 + mh * 4 + mt) * 2 + ks) << 10) + rdb);
  };
  auto read_b = [&](const char* Bb, int nh) __attribute__((always_inline)) {
#pragma unroll
    for (int nt = 0; nt < 2; ++nt)
#pragma unroll
      for (int ks = 0; ks < 2; ++ks)
        bfr[nh][nt][ks] = *(const bf16x8*)(
            Bb + (((wn * 4 + nh * 2 + nt) * 2 + ks) << 10) + rdb);
  };
  auto do_mfma = [&](int mh, int nh) __attribute__((always_inline)) {
    __builtin_amdgcn_s_setprio(1);
#pragma unroll
    for (int mt = 0; mt < 4; ++mt)
#pragma unroll
      for (int nt = 0; nt < 2; ++nt)
#pragma unroll
        for (int ks = 0; ks < 2; ++ks)
          acc[mh * 4 + mt][nh * 2 + nt] = __builtin_amdgcn_mfma_f32_16x16x32_bf16(
              afr[mt][ks], bfr[nh][nt][ks], acc[mh * 4 + mt][nh * 2 + nt],
              0, 0, 0);
    __builtin_amdgcn_s_setprio(0);
  };

  // prologue: tile 0 units, first-needed order A0,B0,B1,A1
  STAGE_A(0, 0); STAGE_B(0, 0); STAGE_B(1, 0); STAGE_A(1, 0);
  CFENCE();

  for (int t = 0; t < 31; ++t) {
    const char* Ab = smem + (t & 1) * 32768;
    const char* Bb = smem + 65536 + (t & 1) * 32768;
    const int nx = t + 1;
    // P1 (mh0,nh0): needs A0,B0 of t (oldest 4 of 8 in flight)
    __builtin_amdgcn_s_waitcnt(WAIT_VM4); CFENCE();
    __builtin_amdgcn_s_barrier(); CFENCE();
    read_a(Ab, 0); read_b(Bb, 0);
    STAGE_A(0, nx); CFENCE();
    do_mfma(0, 0);
    // P2 (mh0,nh1): needs B1 of t
    __builtin_amdgcn_s_waitcnt(WAIT_VM4); CFENCE();
    __builtin_amdgcn_s_barrier(); CFENCE();
    read_b(Bb, 1);
    STAGE_B(0, nx); CFENCE();
    do_mfma(0, 1);
    // P3 (mh1,nh0): needs A1 of t
    __builtin_amdgcn_s_waitcnt(WAIT_VM4); CFENCE();
    __builtin_amdgcn_s_barrier(); CFENCE();
    read_a(Ab, 1);
    STAGE_B(1, nx); CFENCE();
    do_mfma(1, 0);
    // P4 (mh1,nh1): all in registers
    __builtin_amdgcn_s_barrier(); CFENCE();
    STAGE_A(1, nx); CFENCE();
    do_mfma(1, 1);
  }
  {  // peeled last tile (t=31, buf1): drain 4 -> 2 -> 0
    const char* Ab = smem + 32768;
    const char* Bb = smem + 65536 + 32768;
    __builtin_amdgcn_s_waitcnt(WAIT_VM4); CFENCE();
    __builtin_amdgcn_s_barrier(); CFENCE();
    read_a(Ab, 0); read_b(Bb, 0);
    do_mfma(0, 0);
    __builtin_amdgcn_s_waitcnt(WAIT_VM2); CFENCE();
    __builtin_amdgcn_s_barrier(); CFENCE();
    read_b(Bb, 1);
    do_mfma(0, 1);
    __builtin_amdgcn_s_waitcnt(WAIT_VM0); CFENCE();
    __builtin_amdgcn_s_barrier(); CFENCE();
    read_a(Ab, 1);
    do_mfma(1, 0);
    do_mfma(1, 1);
  }
#undef STAGE_A
#undef STAGE_B

  // epilogue: RoPE on head-first-half chunks of Q/K, then region stores
  const int cbase = n0 + wn * 64;
  if (cbase < 2560 && (cbase & 127) == 0) {  // chunk covers head d=0..63
#pragma unroll
    for (int nt = 0; nt < 2; ++nt) {
      const int d = nt * 16 + l16;  // 0..31, pairs with acc[mt][nt+2]
      const float invf = exp2f(-(float)d * 0.41524101186091903f);  // 1e4^(-d/32)
#pragma unroll
      for (int mt = 0; mt < 8; ++mt)
#pragma unroll
        for (int r = 0; r < 4; ++r) {
          const int pos = (m0 + wm * 128 + mt * 16 + quad * 4 + r) & (S_LEN - 1);
          float s, c;
          __sincosf((float)pos * invf, &s, &c);
          const float x1 = acc[mt][nt][r], x2 = acc[mt][nt + 2][r];
          acc[mt][nt][r]     = x1 * c - x2 * s;
          acc[mt][nt + 2][r] = x2 * c + x1 * s;
        }
    }
  }
#pragma unroll
  for (int mt = 0; mt < 8; ++mt) {
    const int row0 = m0 + wm * 128 + mt * 16 + quad * 4;
#pragma unroll
    for (int nt = 0; nt < 4; ++nt) {
      const int col16 = cbase + nt * 16;  // 16-col chunk, region-uniform
      if (col16 < 2048) {                 // Q: [tok][2048]
#pragma unroll
        for (int r = 0; r < 4; ++r)
          Qo[(size_t)(row0 + r) * 2048 + col16 + l16] = (bf16)acc[mt][nt][r];
      } else if (col16 < 2560) {          // K: [tok][512]
#pragma unroll
        for (int r = 0; r < 4; ++r)
          Ko[(size_t)(row0 + r) * 512 + col16 - 2048 + l16] = (bf16)acc[mt][nt][r];
      } else {                            // V: transposed vt[(b*4+kv)*128+d][s]
        const int colv = col16 + l16 - 2560;
        const int b = row0 >> 11, s0 = row0 & (S_LEN - 1);
        bf16x4 tq = {(bf16)acc[mt][nt][0], (bf16)acc[mt][nt][1],
                     (bf16)acc[mt][nt][2], (bf16)acc[mt][nt][3]};
        *(bf16x4*)(Vt + ((size_t)(b * NH_KV + (colv >> 7)) * HD_ + (colv & 127))
                        * S_LEN + s0) = tq;
      }
    }
  }
}

// ---------------- flash attention, S^T formulation --------------------------
#define KS_STRIDE 136   // 64 keys x 128 d, +8 pad (2-way banks = free)
#define VT_STRIDE 72    // 128 d x 64 keys, +8 pad

__global__ __launch_bounds__(256)
void attn_kernel(const bf16* __restrict__ Qg, const bf16* __restrict__ Kg,
                 const bf16* __restrict__ Vtg, bf16* __restrict__ Og) {
  __shared__ __align__(16) bf16 Ks[64 * KS_STRIDE];   // K tile [key][d]
  __shared__ __align__(16) bf16 Vt[128 * VT_STRIDE];  // V^T tile [d][key]
#if !HAVE_MFMA16
  __shared__ __align__(16) bf16 Pb[4][16 * 72];
#endif
  const int tid  = threadIdx.x;
  const int wave = tid >> 6, lane = tid & 63;
  const int quad = lane >> 4, l16 = lane & 15;
  const int qt = blockIdx.x, h = blockIdx.y, b = blockIdx.z;
  const int kv = h >> 2;
  const int q0 = qt * 64;
  const int tok0 = b * S_LEN;
  const float scale = 0.08838834764831845f;  // 1/sqrt(128)
  const int q = q0 + wave * 16 + l16;

  bf16x8 qf[4];
  {
    const bf16* qp = Qg + (size_t)(tok0 + q) * (NH_Q * HD_) + h * HD_ + quad * 8;
#pragma unroll
    for (int kb = 0; kb < 4; ++kb) qf[kb] = *(const bf16x8*)(qp + kb * 32);
  }

  f32x4 o[8];
#pragma unroll
  for (int dt = 0; dt < 8; ++dt) o[dt] = (f32x4){0.f, 0.f, 0.f, 0.f};
  float m_run = -__builtin_inff(), l_run = 0.f;

  int kt_begin = q0 - WIN;
  if (kt_begin < 0) kt_begin = 0;
  const int kt_end = q0 + 64;
  const bf16* vt_base = Vtg + (size_t)(b * NH_KV + kv) * HD_ * S_LEN;

  for (int kt = kt_begin; kt < kt_end; kt += 64) {
    __syncthreads();
#pragma unroll
    for (int it = 0; it < 4; ++it) {
      int vid = tid + it * 256;
      int key = vid >> 4, dblk = vid & 15;
      bf16x8 v = *(const bf16x8*)(Kg + (size_t)(tok0 + kt + key) * (NH_KV * HD_)
                                  + kv * HD_ + dblk * 8);
      *(bf16x8*)&Ks[key * KS_STRIDE + dblk * 8] = v;
    }
#pragma unroll
    for (int it = 0; it < 4; ++it) {
      int vid = tid + it * 256;
      int d = vid >> 3, kblk = vid & 7;
      bf16x8 v = *(const bf16x8*)(vt_base + (size_t)d * S_LEN + kt + kblk * 8);
      *(bf16x8*)&Vt[d * VT_STRIDE + kblk * 8] = v;
    }
    __syncthreads();

    f32x4 st[4];
#pragma unroll
    for (int nt = 0; nt < 4; ++nt) {
      f32x4 acc = (f32x4){0.f, 0.f, 0.f, 0.f};
#pragma unroll
      for (int kb = 0; kb < 4; ++kb) {
        bf16x8 kf = *(const bf16x8*)&Ks[(nt * 16 + l16) * KS_STRIDE + kb * 32 + quad * 8];
        acc = __builtin_amdgcn_mfma_f32_16x16x32_bf16(kf, qf[kb], acc, 0, 0, 0);
      }
      st[nt] = acc;
    }
#pragma unroll
    for (int nt = 0; nt < 4; ++nt)
#pragma unroll
      for (int r = 0; r < 4; ++r) {
        int key = kt + nt * 16 + quad * 4 + r;
        bool ok = (key <= q) && (key > q - WIN);
        st[nt][r] = ok ? st[nt][r] * scale : -__builtin_inff();
      }
    float mx = -__builtin_inff();
#pragma unroll
    for (int nt = 0; nt < 4; ++nt)
#pragma unroll
      for (int r = 0; r < 4; ++r) mx = fmaxf(mx, st[nt][r]);
    mx = fmaxf(mx, __shfl_xor(mx, 16, 64));
    mx = fmaxf(mx, __shfl_xor(mx, 32, 64));
    float mnew = fmaxf(m_run, mx);
    float msub = (mnew == -__builtin_inff()) ? 0.f : mnew;
    float alpha = __expf(m_run - msub);
    m_run = mnew;
    float p[4][4], psum = 0.f;
#pragma unroll
    for (int nt = 0; nt < 4; ++nt)
#pragma unroll
      for (int r = 0; r < 4; ++r) {
        p[nt][r] = __expf(st[nt][r] - msub);
        psum += p[nt][r];
      }
    psum += __shfl_xor(psum, 16, 64);
    psum += __shfl_xor(psum, 32, 64);
    l_run = l_run * alpha + psum;
#pragma unroll
    for (int dt = 0; dt < 8; ++dt) o[dt] *= alpha;

#if HAVE_MFMA16
    s16x4 pb[4];
#pragma unroll
    for (int nt = 0; nt < 4; ++nt)
#pragma unroll
      for (int r = 0; r < 4; ++r) {
        union { __bf16 h; short s; } u;
        u.h = (bf16)p[nt][r];
        pb[nt][r] = u.s;
      }
#pragma unroll
    for (int dt = 0; dt < 8; ++dt)
#pragma unroll
      for (int nt = 0; nt < 4; ++nt) {
        s16x4 vf = *(const s16x4*)&Vt[(dt * 16 + l16) * VT_STRIDE + nt * 16 + quad * 4];
        o[dt] = __builtin_amdgcn_mfma_f32_16x16x16bf16_1k(vf, pb[nt], o[dt], 0, 0, 0);
      }
#else
#pragma unroll
    for (int nt = 0; nt < 4; ++nt) {
      bf16x4 t;
#pragma unroll
      for (int r = 0; r < 4; ++r) t[r] = (bf16)p[nt][r];
      *(bf16x4*)&Pb[wave][l16 * 72 + nt * 16 + quad * 4] = t;
    }
    __syncthreads();
    bf16x8 pf[2];
    pf[0] = *(const bf16x8*)&Pb[wave][l16 * 72 + quad * 8];
    pf[1] = *(const bf16x8*)&Pb[wave][l16 * 72 + 32 + quad * 8];
#pragma unroll
    for (int dt = 0; dt < 8; ++dt)
#pragma unroll
      for (int kb = 0; kb < 2; ++kb) {
        bf16x8 vf = *(const bf16x8*)&Vt[(dt * 16 + l16) * VT_STRIDE + kb * 32 + quad * 8];
        o[dt] = __builtin_amdgcn_mfma_f32_16x16x32_bf16(vf, pf[kb], o[dt], 0, 0, 0);
      }
#endif
  }

  float inv = 1.f / l_run;
  __syncthreads();
#pragma unroll
  for (int dt = 0; dt < 8; ++dt) {
    bf16x4 t;
#pragma unroll
    for (int r = 0; r < 4; ++r) t[r] = (bf16)(o[dt][r] * inv);
    *(bf16x4*)&Ks[(wave * 16 + l16) * KS_STRIDE + dt * 16 + quad * 4] = t;
  }
  __syncthreads();
#pragma unroll
  for (int it = 0; it < 4; ++it) {
    int idx = tid + it * 256;
    int row = idx >> 4, chunk = idx & 15;
    bf16x8 v = *(const bf16x8*)&Ks[row * KS_STRIDE + chunk * 8];
    *(bf16x8*)(Og + (size_t)(tok0 + q0 + row) * (NH_Q * HD_) + h * HD_ + chunk * 8) = v;
  }
}

// ---------------- launcher ----------------
extern "C" void kernel_launch(void* const* d_in, const int* in_sizes, int n_in,
                              void* d_out, int out_size, void* d_ws, size_t ws_size,
                              hipStream_t stream) {
  const float* hs = (const float*)d_in[0];
  const float* Wq = (const float*)d_in[1];
  const float* Wk = (const float*)d_in[2];
  const float* Wv = (const float*)d_in[3];
  const float* Wo = (const float*)d_in[4];
  float* out = (float*)d_out;

  char* w = (char*)d_ws;
  bf16* hsb = (bf16*)w; w += (size_t)NTOK * 2048 * 2;   // 16.8 MB
  bf16* wqb = (bf16*)w; w += (size_t)2048 * 2048 * 2;   //  8.4 MB
  bf16* wkb = (bf16*)w; w += (size_t)512 * 2048 * 2;    //  2.1 MB
  bf16* wvb = (bf16*)w; w += (size_t)512 * 2048 * 2;    //  2.1 MB
  bf16* wob = (bf16*)w; w += (size_t)2048 * 2048 * 2;   //  8.4 MB
  bf16* qb  = (bf16*)w; w += (size_t)NTOK * 2048 * 2;   // 16.8 MB
  bf16* kb  = (bf16*)w; w += (size_t)NTOK * 512 * 2;    //  4.2 MB
  bf16* vtb = (bf16*)w; w += (size_t)NTOK * 512 * 2;    //  4.2 MB
  bf16* ab  = hsb;  // alias: hs_bf16 dead after QKV GEMM

  cvt_all<<<18874368 / 1024, 256, 0, stream>>>(hs, Wq, Wk, Wv, Wo,
                                               hsb, wqb, wkb, wvb, wob);

  gemm_qkv8<<<dim3(12, 16), 512, 0, stream>>>(hsb, wqb, wkb, wvb,
                                              qb, kb, vtb);

  attn_kernel<<<dim3(S_LEN / 64, NH_Q, 2), 256, 0, stream>>>(qb, kb, vtb, ab);

  gemm_bt<float><<<dim3(2048 / 128, NTOK / 128), 256, 0, stream>>>(
      ab, wob, out, NTOK, 2048, 2048);
}

// Round 2
// 256.414 us; speedup vs baseline: 1.0810x; 1.0293x over previous
//
#include <hip/hip_runtime.h>
#include <cstdint>
#include <cstddef>

typedef __bf16 bf16;
typedef __attribute__((ext_vector_type(8))) __bf16 bf16x8;
typedef __attribute__((ext_vector_type(4))) __bf16 bf16x4;
typedef __attribute__((ext_vector_type(4))) float f32x4;
typedef __attribute__((ext_vector_type(4))) short s16x4;

#define S_LEN   2048
#define WIN     512
#define NH_Q    16
#define NH_KV   4
#define HD_     128
#define NTOK    4096   // B * S

#if defined(__has_builtin)
#if __has_builtin(__builtin_amdgcn_mfma_f32_16x16x16bf16_1k)
#define HAVE_MFMA16 1
#endif
#endif
#ifndef HAVE_MFMA16
#define HAVE_MFMA16 0
#endif

// s_waitcnt immediates (gfx9 encoding: vm[3:0]=s[3:0], exp=s[6:4],
// lgkm=s[11:8], vm[5:4]=s[15:14]); non-waited fields all-ones.
#define WAIT_VM4   0x0F74  // vmcnt<=4
#define WAIT_VM3   0x0F73  // vmcnt<=3
#define WAIT_VM2   0x0F72  // vmcnt<=2
#define WAIT_VM0   0x0F70  // vmcnt<=0
#define CFENCE() __asm__ __volatile__("" ::: "memory")

// async global->LDS, 16B per lane; LDS dest = wave-uniform base + lane*16
__device__ __forceinline__ void async_copy16(const void* g, void* l) {
  __builtin_amdgcn_global_load_lds(
      (const __attribute__((address_space(1))) void*)g,
      (__attribute__((address_space(3))) void*)l, 16, 0, 0);
}

// ---------------- fp32 -> bf16 convert, all 5 arrays in one launch ----------
__global__ __launch_bounds__(256)
void cvt_all(const float* __restrict__ hs, const float* __restrict__ wq,
             const float* __restrict__ wk, const float* __restrict__ wv,
             const float* __restrict__ wo, bf16* __restrict__ hsb,
             bf16* __restrict__ wqb, bf16* __restrict__ wkb,
             bf16* __restrict__ wvb, bf16* __restrict__ wob) {
  long i = ((long)blockIdx.x * 256 + threadIdx.x) * 4;  // < 18874368
  const float* in;
  bf16* out;
  if (i < 8388608)       { in = hs + i;            out = hsb + i; }
  else if (i < 12582912) { in = wq + (i - 8388608); out = wqb + (i - 8388608); }
  else if (i < 13631488) { in = wk + (i - 12582912); out = wkb + (i - 12582912); }
  else if (i < 14680064) { in = wv + (i - 13631488); out = wvb + (i - 13631488); }
  else                   { in = wo + (i - 14680064); out = wob + (i - 14680064); }
  float4 v = *(const float4*)in;
  bf16x4 t = {(bf16)v.x, (bf16)v.y, (bf16)v.z, (bf16)v.w};
  *(bf16x4*)out = t;
}

// ---------------- GEMM (barrier-style, R6): in-run CONTROL ------------------
// 128x128 tile, BK=32, dbuf, swizzled LDS (0 conflicts, R6-verified).
template <typename OutT>
__global__ __launch_bounds__(256)
void gemm_bt(const bf16* __restrict__ A, const bf16* __restrict__ W,
             OutT* __restrict__ C, int M, int N, int K) {
  __shared__ __align__(16) bf16 As[2][128 * 32];
  __shared__ __align__(16) bf16 Bs[2][128 * 32];
  const int tid  = threadIdx.x;
  const int wave = tid >> 6, lane = tid & 63;
  const int quad = lane >> 4, l16 = lane & 15;
  const int wm = wave >> 1, wn = wave & 1;
  const int m0 = blockIdx.y * 128, n0 = blockIdx.x * 128;
  const int lrow = lane >> 2;
  const int lcol = (((lane & 3) + ((lane >> 3) & 3)) & 3) * 8;  // swizzled src k
  const int gfrag = ((quad - ((l16 >> 1) & 3)) & 3) * 8;        // swizzled read k

  f32x4 acc[4][4];
#pragma unroll
  for (int i = 0; i < 4; ++i)
#pragma unroll
    for (int j = 0; j < 4; ++j) acc[i][j] = (f32x4){0.f, 0.f, 0.f, 0.f};

  auto stage = [&](int buf, int k0) {
#pragma unroll
    for (int it = 0; it < 2; ++it) {
      const int c   = it * 4 + wave;
      const int row = c * 16 + lrow;
      async_copy16(A + (size_t)(m0 + row) * K + k0 + lcol, &As[buf][c * 512]);
      async_copy16(W + (size_t)(n0 + row) * K + k0 + lcol, &Bs[buf][c * 512]);
    }
  };

  stage(0, 0);
  __syncthreads();
  for (int k0 = 0; k0 < K; k0 += 32) {
    const int cur = (k0 >> 5) & 1;
    if (k0 + 32 < K) stage(cur ^ 1, k0 + 32);
    bf16x8 af[4], bfr[4];
#pragma unroll
    for (int mt = 0; mt < 4; ++mt)
      af[mt] = *(const bf16x8*)&As[cur][(wm * 64 + mt * 16 + l16) * 32 + gfrag];
#pragma unroll
    for (int nt = 0; nt < 4; ++nt)
      bfr[nt] = *(const bf16x8*)&Bs[cur][(wn * 64 + nt * 16 + l16) * 32 + gfrag];
#pragma unroll
    for (int mt = 0; mt < 4; ++mt)
#pragma unroll
      for (int nt = 0; nt < 4; ++nt)
        acc[mt][nt] = __builtin_amdgcn_mfma_f32_16x16x32_bf16(
            af[mt], bfr[nt], acc[mt][nt], 0, 0, 0);
    __syncthreads();
  }
#pragma unroll
  for (int mt = 0; mt < 4; ++mt)
#pragma unroll
    for (int nt = 0; nt < 4; ++nt)
#pragma unroll
      for (int r = 0; r < 4; ++r) {
        const int row = m0 + wm * 64 + mt * 16 + quad * 4 + r;
        const int col = n0 + wn * 64 + nt * 16 + l16;
        C[(size_t)row * N + col] = (OutT)acc[mt][nt][r];
      }
}

// ---------------- fused QKV GEMM: 256x192 tile, 256 blocks = 1/CU -----------
// Grid 16x16 = 256 blocks exactly fills 256 CUs (round-1 counters: 192-block
// grid left 25% of the machine idle; MfmaUtil 32% = 45% per-active-CU x 0.75).
// Wave grid 4(M)x2(N); wave wn owns interleaved 16-col chunks {wn, wn+2} of
// each 64-col block so RoPE pairs (d, d+32) stay in-wave: acc[mt][2b] (col
// cb+wn*16+l16) pairs acc[mt][2b+1] (col +32). 4-phase counted-vmcnt schedule
// (T3/T4), st_16x32 swizzle (T2, same formulas as R6-verified), setprio (T5),
// bijective XCD swizzle over 256 = 8x32 (T1). Stage 7 units/wave/tile in
// first-needed order A0(2),B0(1),B12(2),A1(2): steady waits vm4/vm4/vm3/none,
// never 0 in main loop; drain 4->2->0 in peeled last tile.
__global__ __launch_bounds__(512, 2)
void gemm_qkv9(const bf16* __restrict__ A, const bf16* __restrict__ Wq,
               const bf16* __restrict__ Wk, const bf16* __restrict__ Wv,
               bf16* __restrict__ Qo, bf16* __restrict__ Ko,
               bf16* __restrict__ Vt) {
  __shared__ __align__(16) char smem[114688];  // A[2]: 0/32K, B[2]: 64K/88K
  const int tid  = threadIdx.x;
  const int wave = tid >> 6, lane = tid & 63;
  const int quad = lane >> 4, l16 = lane & 15;
  const int wm = wave >> 1, wn = wave & 1;   // 4x2 wave grid, 64 rows x 96 cols

  // XCD-swizzled tile coords (grid 16x16 = 256 = 8 XCD x 32, bijective)
  const int flat = blockIdx.y * 16 + blockIdx.x;
  const int swz  = (flat & 7) * 32 + (flat >> 3);
  const int m0 = (swz >> 4) * 256;
  const int n0 = (swz & 15) * 192;

  // swizzled within-subtile read byte offset (st_16x32, R6-verified formulas)
  const int rdb = (l16 * 64 + quad * 16) ^ ((l16 & 8) << 2);

  // ---- stage source (pre-swizzled global col) + LDS dest, per unit ----
  const int srow = lane >> 2;
  const int scol = ((lane & 3) * 8) ^ ((lane >> 5) << 4);

  // A: 32 units (16-row block rb x k-half), 4/wave. P1 region rows ≡0..31
  // mod 64 (rb mod 4 in {0,1}); P3 region rb mod 4 in {2,3}.
  const int rbA0 = (wave >> 1) * 4 + (wave & 1);
  const int rbA1 = rbA0 + 2;
  const bf16* a0p = A + (size_t)(m0 + rbA0 * 16 + srow) * 2048 + scol;
  const bf16* a1p = A + (size_t)(m0 + rbA1 * 16 + srow) * 2048 + scol;
  const int da0 = (rbA0 * 2) << 10;
  const int da1 = (rbA1 * 2) << 10;

  // B: 24 units (12 row-blocks x 2 k-halves), 3/wave. P1 region = rows 0-63
  // (8 units, 1/wave); P2 region = rows 64-191 (16 units, 2/wave). 16-row
  // blocks never straddle the Q|K|V boundaries (2048/2560 are 16-aligned).
  const int rbB0 = wave >> 1, khB0 = wave & 1;
  const int rbB1 = 4 + wave;
  const int nrow0 = n0 + rbB0 * 16 + srow;
  const int nrow1 = n0 + rbB1 * 16 + srow;
  const bf16* b0p = (nrow0 < 2048 ? Wq + (size_t)nrow0 * 2048
                   : nrow0 < 2560 ? Wk + (size_t)(nrow0 - 2048) * 2048
                                  : Wv + (size_t)(nrow0 - 2560) * 2048)
                    + scol + khB0 * 32;
  const bf16* b1p = (nrow1 < 2048 ? Wq + (size_t)nrow1 * 2048
                   : nrow1 < 2560 ? Wk + (size_t)(nrow1 - 2048) * 2048
                                  : Wv + (size_t)(nrow1 - 2560) * 2048)
                    + scol;
  const int db0 = (rbB0 * 2 + khB0) << 10;
  const int db1 = (rbB1 * 2) << 10;

#define STAGE_A0(tt) do { char* _b = smem + ((tt) & 1) * 32768;        \
    async_copy16(a0p + (tt) * 64,      _b + da0);                      \
    async_copy16(a0p + (tt) * 64 + 32, _b + da0 + 1024); } while (0)
#define STAGE_A1(tt) do { char* _b = smem + ((tt) & 1) * 32768;        \
    async_copy16(a1p + (tt) * 64,      _b + da1);                      \
    async_copy16(a1p + (tt) * 64 + 32, _b + da1 + 1024); } while (0)
#define STAGE_B0(tt) do { char* _b = smem + 65536 + ((tt) & 1) * 24576; \
    async_copy16(b0p + (tt) * 64,      _b + db0); } while (0)
#define STAGE_B12(tt) do { char* _b = smem + 65536 + ((tt) & 1) * 24576; \
    async_copy16(b1p + (tt) * 64,      _b + db1);                      \
    async_copy16(b1p + (tt) * 64 + 32, _b + db1 + 1024); } while (0)

  f32x4 acc[4][6];
#pragma unroll
  for (int i = 0; i < 4; ++i)
#pragma unroll
    for (int j = 0; j < 6; ++j) acc[i][j] = (f32x4){0.f, 0.f, 0.f, 0.f};

  bf16x8 afr[2][2];   // current mt-pair (mh half)
  bf16x8 bfr[6][2];   // all 6 interleaved n-chunks, held across K-tile

  auto read_a = [&](const char* Ab, int mh) __attribute__((always_inline)) {
#pragma unroll
    for (int mt2 = 0; mt2 < 2; ++mt2)
#pragma unroll
      for (int ks = 0; ks < 2; ++ks)
        afr[mt2][ks] = *(const bf16x8*)(
            Ab + (((wm * 4 + mh * 2 + mt2) * 2 + ks) << 10) + rdb);
  };
  // chunk index of frag j: cc = (j>>1)*4 + (j&1)*2 + wn
  auto read_b = [&](const char* Bb, int jlo, int jhi) __attribute__((always_inline)) {
#pragma unroll
    for (int j = 0; j < 6; ++j) {
      if (j < jlo || j > jhi) continue;
      const int cc = (j >> 1) * 4 + (j & 1) * 2 + wn;
#pragma unroll
      for (int ks = 0; ks < 2; ++ks)
        bfr[j][ks] = *(const bf16x8*)(Bb + ((cc * 2 + ks) << 10) + rdb);
    }
  };
  auto do_mfma = [&](int mh, int jlo, int jhi) __attribute__((always_inline)) {
    __builtin_amdgcn_s_setprio(1);
#pragma unroll
    for (int mt2 = 0; mt2 < 2; ++mt2)
#pragma unroll
      for (int j = 0; j < 6; ++j) {
        if (j < jlo || j > jhi) continue;
#pragma unroll
        for (int ks = 0; ks < 2; ++ks)
          acc[mh * 2 + mt2][j] = __builtin_amdgcn_mfma_f32_16x16x32_bf16(
              afr[mt2][ks], bfr[j][ks], acc[mh * 2 + mt2][j], 0, 0, 0);
      }
    __builtin_amdgcn_s_setprio(0);
  };

  // prologue: tile 0, first-needed order
  STAGE_A0(0); STAGE_B0(0); STAGE_B12(0); STAGE_A1(0);
  CFENCE();

  for (int t = 0; t < 31; ++t) {
    const char* Ab = smem + (t & 1) * 32768;
    const char* Bb = smem + 65536 + (t & 1) * 24576;
    const int nx = t + 1;
    // P1: needs A0,B0 of t (first 3 of 7) -> vmcnt(4)
    __builtin_amdgcn_s_waitcnt(WAIT_VM4); CFENCE();
    __builtin_amdgcn_s_barrier(); CFENCE();
    read_a(Ab, 0); read_b(Bb, 0, 1);
    STAGE_A0(nx); CFENCE();
    do_mfma(0, 0, 1);
    // P2: needs B12 of t -> leave A1(t)+A0(t+1) = vmcnt(4)
    __builtin_amdgcn_s_waitcnt(WAIT_VM4); CFENCE();
    __builtin_amdgcn_s_barrier(); CFENCE();
    read_b(Bb, 2, 5);
    STAGE_B0(nx); CFENCE();
    do_mfma(0, 2, 5);
    // P3: needs A1 of t -> leave A0(2)+B0(1) of t+1 = vmcnt(3)
    __builtin_amdgcn_s_waitcnt(WAIT_VM3); CFENCE();
    __builtin_amdgcn_s_barrier(); CFENCE();
    read_a(Ab, 1);
    STAGE_B12(nx); CFENCE();
    do_mfma(1, 0, 1);
    // P4: all in registers
    __builtin_amdgcn_s_barrier(); CFENCE();
    STAGE_A1(nx); CFENCE();
    do_mfma(1, 2, 5);
  }
  {  // peeled last tile (t=31, buf1): drain 4 -> 2 -> 0
    const char* Ab = smem + 32768;
    const char* Bb = smem + 65536 + 24576;
    __builtin_amdgcn_s_waitcnt(WAIT_VM4); CFENCE();
    __builtin_amdgcn_s_barrier(); CFENCE();
    read_a(Ab, 0); read_b(Bb, 0, 1);
    do_mfma(0, 0, 1);
    __builtin_amdgcn_s_waitcnt(WAIT_VM2); CFENCE();
    __builtin_amdgcn_s_barrier(); CFENCE();
    read_b(Bb, 2, 5);
    do_mfma(0, 2, 5);
    __builtin_amdgcn_s_waitcnt(WAIT_VM0); CFENCE();
    __builtin_amdgcn_s_barrier(); CFENCE();
    read_a(Ab, 1);
    do_mfma(1, 0, 1);
    do_mfma(1, 2, 5);
  }
#undef STAGE_A0
#undef STAGE_A1
#undef STAGE_B0
#undef STAGE_B12

  // epilogue: RoPE on rotary 64-blocks (cb ≡ 0 mod 128, cb < 2560).
  // frag 2b holds col cb + d, frag 2b+1 holds col cb + d + 32, d = wn*16+l16.
  {
    const float d = (float)(wn * 16 + l16);
    const float invf = exp2f(-d * 0.41524101186091903f);  // 1e4^(-d/32)
#pragma unroll
    for (int b = 0; b < 3; ++b) {
      const int cb = n0 + b * 64;
      if (cb < 2560 && (cb & 127) == 0) {
#pragma unroll
        for (int mt = 0; mt < 4; ++mt)
#pragma unroll
          for (int r = 0; r < 4; ++r) {
            const int pos = (m0 + wm * 64 + mt * 16 + quad * 4 + r) & (S_LEN - 1);
            float s, c;
            __sincosf((float)pos * invf, &s, &c);
            const float x1 = acc[mt][2 * b][r], x2 = acc[mt][2 * b + 1][r];
            acc[mt][2 * b][r]     = x1 * c - x2 * s;
            acc[mt][2 * b + 1][r] = x2 * c + x1 * s;
          }
      }
    }
  }
#pragma unroll
  for (int mt = 0; mt < 4; ++mt) {
    const int row0 = m0 + wm * 64 + mt * 16 + quad * 4;
#pragma unroll
    for (int j = 0; j < 6; ++j) {
      const int col16 = n0 + (j >> 1) * 64 + ((j & 1) * 2 + wn) * 16;
      if (col16 < 2048) {                 // Q: [tok][2048]
#pragma unroll
        for (int r = 0; r < 4; ++r)
          Qo[(size_t)(row0 + r) * 2048 + col16 + l16] = (bf16)acc[mt][j][r];
      } else if (col16 < 2560) {          // K: [tok][512]
#pragma unroll
        for (int r = 0; r < 4; ++r)
          Ko[(size_t)(row0 + r) * 512 + col16 - 2048 + l16] = (bf16)acc[mt][j][r];
      } else {                            // V: transposed vt[(b*4+kv)*128+d][s]
        const int colv = col16 + l16 - 2560;
        const int bb = row0 >> 11, s0 = row0 & (S_LEN - 1);
        bf16x4 tq = {(bf16)acc[mt][j][0], (bf16)acc[mt][j][1],
                     (bf16)acc[mt][j][2], (bf16)acc[mt][j][3]};
        *(bf16x4*)(Vt + ((size_t)(bb * NH_KV + (colv >> 7)) * HD_ + (colv & 127))
                        * S_LEN + s0) = tq;
      }
    }
  }
}

// ---------------- flash attention, S^T formulation --------------------------
#define KS_STRIDE 136   // 64 keys x 128 d, +8 pad (2-way banks = free)
#define VT_STRIDE 72    // 128 d x 64 keys, +8 pad

__global__ __launch_bounds__(256)
void attn_kernel(const bf16* __restrict__ Qg, const bf16* __restrict__ Kg,
                 const bf16* __restrict__ Vtg, bf16* __restrict__ Og) {
  __shared__ __align__(16) bf16 Ks[64 * KS_STRIDE];   // K tile [key][d]
  __shared__ __align__(16) bf16 Vt[128 * VT_STRIDE];  // V^T tile [d][key]
#if !HAVE_MFMA16
  __shared__ __align__(16) bf16 Pb[4][16 * 72];
#endif
  const int tid  = threadIdx.x;
  const int wave = tid >> 6, lane = tid & 63;
  const int quad = lane >> 4, l16 = lane & 15;
  const int qt = blockIdx.x, h = blockIdx.y, b = blockIdx.z;
  const int kv = h >> 2;
  const int q0 = qt * 64;
  const int tok0 = b * S_LEN;
  const float scale = 0.08838834764831845f;  // 1/sqrt(128)
  const int q = q0 + wave * 16 + l16;

  bf16x8 qf[4];
  {
    const bf16* qp = Qg + (size_t)(tok0 + q) * (NH_Q * HD_) + h * HD_ + quad * 8;
#pragma unroll
    for (int kb = 0; kb < 4; ++kb) qf[kb] = *(const bf16x8*)(qp + kb * 32);
  }

  f32x4 o[8];
#pragma unroll
  for (int dt = 0; dt < 8; ++dt) o[dt] = (f32x4){0.f, 0.f, 0.f, 0.f};
  float m_run = -__builtin_inff(), l_run = 0.f;

  int kt_begin = q0 - WIN;
  if (kt_begin < 0) kt_begin = 0;
  const int kt_end = q0 + 64;
  const bf16* vt_base = Vtg + (size_t)(b * NH_KV + kv) * HD_ * S_LEN;

  for (int kt = kt_begin; kt < kt_end; kt += 64) {
    __syncthreads();
#pragma unroll
    for (int it = 0; it < 4; ++it) {
      int vid = tid + it * 256;
      int key = vid >> 4, dblk = vid & 15;
      bf16x8 v = *(const bf16x8*)(Kg + (size_t)(tok0 + kt + key) * (NH_KV * HD_)
                                  + kv * HD_ + dblk * 8);
      *(bf16x8*)&Ks[key * KS_STRIDE + dblk * 8] = v;
    }
#pragma unroll
    for (int it = 0; it < 4; ++it) {
      int vid = tid + it * 256;
      int d = vid >> 3, kblk = vid & 7;
      bf16x8 v = *(const bf16x8*)(vt_base + (size_t)d * S_LEN + kt + kblk * 8);
      *(bf16x8*)&Vt[d * VT_STRIDE + kblk * 8] = v;
    }
    __syncthreads();

    f32x4 st[4];
#pragma unroll
    for (int nt = 0; nt < 4; ++nt) {
      f32x4 acc = (f32x4){0.f, 0.f, 0.f, 0.f};
#pragma unroll
      for (int kb = 0; kb < 4; ++kb) {
        bf16x8 kf = *(const bf16x8*)&Ks[(nt * 16 + l16) * KS_STRIDE + kb * 32 + quad * 8];
        acc = __builtin_amdgcn_mfma_f32_16x16x32_bf16(kf, qf[kb], acc, 0, 0, 0);
      }
      st[nt] = acc;
    }
#pragma unroll
    for (int nt = 0; nt < 4; ++nt)
#pragma unroll
      for (int r = 0; r < 4; ++r) {
        int key = kt + nt * 16 + quad * 4 + r;
        bool ok = (key <= q) && (key > q - WIN);
        st[nt][r] = ok ? st[nt][r] * scale : -__builtin_inff();
      }
    float mx = -__builtin_inff();
#pragma unroll
    for (int nt = 0; nt < 4; ++nt)
#pragma unroll
      for (int r = 0; r < 4; ++r) mx = fmaxf(mx, st[nt][r]);
    mx = fmaxf(mx, __shfl_xor(mx, 16, 64));
    mx = fmaxf(mx, __shfl_xor(mx, 32, 64));
    float mnew = fmaxf(m_run, mx);
    float msub = (mnew == -__builtin_inff()) ? 0.f : mnew;
    float alpha = __expf(m_run - msub);
    m_run = mnew;
    float p[4][4], psum = 0.f;
#pragma unroll
    for (int nt = 0; nt < 4; ++nt)
#pragma unroll
      for (int r = 0; r < 4; ++r) {
        p[nt][r] = __expf(st[nt][r] - msub);
        psum += p[nt][r];
      }
    psum += __shfl_xor(psum, 16, 64);
    psum += __shfl_xor(psum, 32, 64);
    l_run = l_run * alpha + psum;
#pragma unroll
    for (int dt = 0; dt < 8; ++dt) o[dt] *= alpha;

#if HAVE_MFMA16
    s16x4 pb[4];
#pragma unroll
    for (int nt = 0; nt < 4; ++nt)
#pragma unroll
      for (int r = 0; r < 4; ++r) {
        union { __bf16 h; short s; } u;
        u.h = (bf16)p[nt][r];
        pb[nt][r] = u.s;
      }
#pragma unroll
    for (int dt = 0; dt < 8; ++dt)
#pragma unroll
      for (int nt = 0; nt < 4; ++nt) {
        s16x4 vf = *(const s16x4*)&Vt[(dt * 16 + l16) * VT_STRIDE + nt * 16 + quad * 4];
        o[dt] = __builtin_amdgcn_mfma_f32_16x16x16bf16_1k(vf, pb[nt], o[dt], 0, 0, 0);
      }
#else
#pragma unroll
    for (int nt = 0; nt < 4; ++nt) {
      bf16x4 t;
#pragma unroll
      for (int r = 0; r < 4; ++r) t[r] = (bf16)p[nt][r];
      *(bf16x4*)&Pb[wave][l16 * 72 + nt * 16 + quad * 4] = t;
    }
    __syncthreads();
    bf16x8 pf[2];
    pf[0] = *(const bf16x8*)&Pb[wave][l16 * 72 + quad * 8];
    pf[1] = *(const bf16x8*)&Pb[wave][l16 * 72 + 32 + quad * 8];
#pragma unroll
    for (int dt = 0; dt < 8; ++dt)
#pragma unroll
      for (int kb = 0; kb < 2; ++kb) {
        bf16x8 vf = *(const bf16x8*)&Vt[(dt * 16 + l16) * VT_STRIDE + kb * 32 + quad * 8];
        o[dt] = __builtin_amdgcn_mfma_f32_16x16x32_bf16(vf, pf[kb], o[dt], 0, 0, 0);
      }
#endif
  }

  float inv = 1.f / l_run;
  __syncthreads();
#pragma unroll
  for (int dt = 0; dt < 8; ++dt) {
    bf16x4 t;
#pragma unroll
    for (int r = 0; r < 4; ++r) t[r] = (bf16)(o[dt][r] * inv);
    *(bf16x4*)&Ks[(wave * 16 + l16) * KS_STRIDE + dt * 16 + quad * 4] = t;
  }
  __syncthreads();
#pragma unroll
  for (int it = 0; it < 4; ++it) {
    int idx = tid + it * 256;
    int row = idx >> 4, chunk = idx & 15;
    bf16x8 v = *(const bf16x8*)&Ks[row * KS_STRIDE + chunk * 8];
    *(bf16x8*)(Og + (size_t)(tok0 + q0 + row) * (NH_Q * HD_) + h * HD_ + chunk * 8) = v;
  }
}

// ---------------- launcher ----------------
extern "C" void kernel_launch(void* const* d_in, const int* in_sizes, int n_in,
                              void* d_out, int out_size, void* d_ws, size_t ws_size,
                              hipStream_t stream) {
  const float* hs = (const float*)d_in[0];
  const float* Wq = (const float*)d_in[1];
  const float* Wk = (const float*)d_in[2];
  const float* Wv = (const float*)d_in[3];
  const float* Wo = (const float*)d_in[4];
  float* out = (float*)d_out;

  char* w = (char*)d_ws;
  bf16* hsb = (bf16*)w; w += (size_t)NTOK * 2048 * 2;   // 16.8 MB
  bf16* wqb = (bf16*)w; w += (size_t)2048 * 2048 * 2;   //  8.4 MB
  bf16* wkb = (bf16*)w; w += (size_t)512 * 2048 * 2;    //  2.1 MB
  bf16* wvb = (bf16*)w; w += (size_t)512 * 2048 * 2;    //  2.1 MB
  bf16* wob = (bf16*)w; w += (size_t)2048 * 2048 * 2;   //  8.4 MB
  bf16* qb  = (bf16*)w; w += (size_t)NTOK * 2048 * 2;   // 16.8 MB
  bf16* kb  = (bf16*)w; w += (size_t)NTOK * 512 * 2;    //  4.2 MB
  bf16* vtb = (bf16*)w; w += (size_t)NTOK * 512 * 2;    //  4.2 MB
  bf16* ab  = hsb;  // alias: hs_bf16 dead after QKV GEMM

  cvt_all<<<18874368 / 1024, 256, 0, stream>>>(hs, Wq, Wk, Wv, Wo,
                                               hsb, wqb, wkb, wvb, wob);

  gemm_qkv9<<<dim3(16, 16), 512, 0, stream>>>(hsb, wqb, wkb, wvb,
                                              qb, kb, vtb);

  attn_kernel<<<dim3(S_LEN / 64, NH_Q, 2), 256, 0, stream>>>(qb, kb, vtb, ab);

  gemm_bt<float><<<dim3(2048 / 128, NTOK / 128), 256, 0, stream>>>(
      ab, wob, out, NTOK, 2048, 2048);
}

// Round 3
// 244.213 us; speedup vs baseline: 1.1350x; 1.0500x over previous
//
#include <hip/hip_runtime.h>
#include <cstdint>
#include <cstddef>

typedef __bf16 bf16;
typedef __attribute__((ext_vector_type(8))) __bf16 bf16x8;
typedef __attribute__((ext_vector_type(4))) __bf16 bf16x4;
typedef __attribute__((ext_vector_type(4))) float f32x4;
typedef __attribute__((ext_vector_type(4))) short s16x4;

#define S_LEN   2048
#define WIN     512
#define NH_Q    16
#define NH_KV   4
#define HD_     128
#define NTOK    4096   // B * S

#if defined(__has_builtin)
#if __has_builtin(__builtin_amdgcn_mfma_f32_16x16x16bf16_1k)
#define HAVE_MFMA16 1
#endif
#endif
#ifndef HAVE_MFMA16
#define HAVE_MFMA16 0
#endif

// s_waitcnt immediates (gfx9 encoding: vm[3:0]=s[3:0], exp=s[6:4],
// lgkm=s[11:8], vm[5:4]=s[15:14]); non-waited fields all-ones.
#define WAIT_VM4   0x0F74  // vmcnt<=4
#define WAIT_VM3   0x0F73  // vmcnt<=3
#define WAIT_VM2   0x0F72  // vmcnt<=2
#define WAIT_VM0   0x0F70  // vmcnt<=0
#define CFENCE() __asm__ __volatile__("" ::: "memory")

// async global->LDS, 16B per lane; LDS dest = wave-uniform base + lane*16
__device__ __forceinline__ void async_copy16(const void* g, void* l) {
  __builtin_amdgcn_global_load_lds(
      (const __attribute__((address_space(1))) void*)g,
      (__attribute__((address_space(3))) void*)l, 16, 0, 0);
}

// ---------------- fp32 -> bf16 convert, all 5 arrays in one launch ----------
__global__ __launch_bounds__(256)
void cvt_all(const float* __restrict__ hs, const float* __restrict__ wq,
             const float* __restrict__ wk, const float* __restrict__ wv,
             const float* __restrict__ wo, bf16* __restrict__ hsb,
             bf16* __restrict__ wqb, bf16* __restrict__ wkb,
             bf16* __restrict__ wvb, bf16* __restrict__ wob) {
  long i = ((long)blockIdx.x * 256 + threadIdx.x) * 4;  // < 18874368
  const float* in;
  bf16* out;
  if (i < 8388608)       { in = hs + i;            out = hsb + i; }
  else if (i < 12582912) { in = wq + (i - 8388608); out = wqb + (i - 8388608); }
  else if (i < 13631488) { in = wk + (i - 12582912); out = wkb + (i - 12582912); }
  else if (i < 14680064) { in = wv + (i - 13631488); out = wvb + (i - 13631488); }
  else                   { in = wo + (i - 14680064); out = wob + (i - 14680064); }
  float4 v = *(const float4*)in;
  bf16x4 t = {(bf16)v.x, (bf16)v.y, (bf16)v.z, (bf16)v.w};
  *(bf16x4*)out = t;
}

// ---------------- output GEMM: 256x128 tile, 4-phase schedule, 1 block/CU ---
// Round-2 counters for the old 128x128 2-barrier gemm_bt: MfmaUtil 23%,
// FETCH 69.7MB (2.8x read over-fetch, no XCD swizzle), 625 TF. Rebuild with
// the qkv9-verified structure: grid 16x16 = 256 blocks = 1/CU, 8 waves
// (4Mx2N, 64x64 per wave), BK=64, T2 st_16x32 swizzle (same R6-verified
// formulas), T3/T4 4-phase counted vmcnt (6 stage-units/tile, first-needed
// order A0(2),B0(1),B1(1),A1(2): waits vm3/vm4/vm3/none, never 0 in main
// loop; drain 3->2->0 in peeled tile), T5 setprio, T1 bijective XCD swizzle
// (256 = 8 XCD x 32). Uniform 8 MFMA/phase.
__global__ __launch_bounds__(512, 2)
void gemm_out8(const bf16* __restrict__ A, const bf16* __restrict__ W,
               float* __restrict__ C) {
  __shared__ __align__(16) char smem[98304];  // A[2]: 0/32K, B[2]: 64K/80K
  const int tid  = threadIdx.x;
  const int wave = tid >> 6, lane = tid & 63;
  const int quad = lane >> 4, l16 = lane & 15;
  const int wm = wave >> 1, wn = wave & 1;   // 4x2 wave grid, 64x64 each

  // XCD-swizzled tile coords (grid 16(n) x 16(m) = 256 = 8 XCD x 32)
  const int flat = blockIdx.y * 16 + blockIdx.x;
  const int swz  = (flat & 7) * 32 + (flat >> 3);
  const int m0 = (swz >> 4) * 256;
  const int n0 = (swz & 15) * 128;

  // swizzled within-subtile read byte offset (st_16x32, R6-verified)
  const int rdb = (l16 * 64 + quad * 16) ^ ((l16 & 8) << 2);
  const int srow = lane >> 2;
  const int scol = ((lane & 3) * 8) ^ ((lane >> 5) << 4);

  // A: 32 subtiles (16 row-blocks x 2 k-halves), 4 units/wave.
  // unit [mh][j]: rb = (wave>>1)*4 + mh*2 + j, kh = wave&1.
  const bf16* aptr[2][2];
  int adst[2][2];
#pragma unroll
  for (int mh = 0; mh < 2; ++mh)
#pragma unroll
    for (int j = 0; j < 2; ++j) {
      const int rb = (wave >> 1) * 4 + mh * 2 + j;
      aptr[mh][j] = A + (size_t)(m0 + rb * 16 + srow) * 2048 + scol
                    + (wave & 1) * 32;
      adst[mh][j] = (rb * 2 + (wave & 1)) << 10;
    }
  // B: 16 subtiles (8 col-blocks x 2 k-halves), 2 units/wave.
  // unit [nh]: cb = (wave>>2)*4 + nh*2 + ((wave>>1)&1), kh = wave&1.
  const bf16* bptr[2];
  int bdst[2];
#pragma unroll
  for (int nh = 0; nh < 2; ++nh) {
    const int cb = (wave >> 2) * 4 + nh * 2 + ((wave >> 1) & 1);
    bptr[nh] = W + (size_t)(n0 + cb * 16 + srow) * 2048 + scol
               + (wave & 1) * 32;
    bdst[nh] = (cb * 2 + (wave & 1)) << 10;
  }

#define STAGE_A(mh, tt) do { char* _b = smem + ((tt) & 1) * 32768;      \
    async_copy16(aptr[mh][0] + (tt) * 64, _b + adst[mh][0]);            \
    async_copy16(aptr[mh][1] + (tt) * 64, _b + adst[mh][1]); } while (0)
#define STAGE_B(nh, tt) do { char* _b = smem + 65536 + ((tt) & 1) * 16384; \
    async_copy16(bptr[nh] + (tt) * 64, _b + bdst[nh]); } while (0)

  f32x4 acc[4][4];
#pragma unroll
  for (int i = 0; i < 4; ++i)
#pragma unroll
    for (int j = 0; j < 4; ++j) acc[i][j] = (f32x4){0.f, 0.f, 0.f, 0.f};

  bf16x8 afr[2][2];      // current mh half's A frags
  bf16x8 bfr[2][2][2];   // [nh][nt2][ks], held across K-tile

  auto read_a = [&](const char* Ab, int mh) __attribute__((always_inline)) {
#pragma unroll
    for (int mt2 = 0; mt2 < 2; ++mt2)
#pragma unroll
      for (int ks = 0; ks < 2; ++ks)
        afr[mt2][ks] = *(const bf16x8*)(
            Ab + (((wm * 4 + mh * 2 + mt2) * 2 + ks) << 10) + rdb);
  };
  auto read_b = [&](const char* Bb, int nh) __attribute__((always_inline)) {
#pragma unroll
    for (int nt2 = 0; nt2 < 2; ++nt2)
#pragma unroll
      for (int ks = 0; ks < 2; ++ks)
        bfr[nh][nt2][ks] = *(const bf16x8*)(
            Bb + (((wn * 4 + nh * 2 + nt2) * 2 + ks) << 10) + rdb);
  };
  auto do_mfma = [&](int mh, int nh) __attribute__((always_inline)) {
    __builtin_amdgcn_s_setprio(1);
#pragma unroll
    for (int mt2 = 0; mt2 < 2; ++mt2)
#pragma unroll
      for (int nt2 = 0; nt2 < 2; ++nt2)
#pragma unroll
        for (int ks = 0; ks < 2; ++ks)
          acc[mh * 2 + mt2][nh * 2 + nt2] = __builtin_amdgcn_mfma_f32_16x16x32_bf16(
              afr[mt2][ks], bfr[nh][nt2][ks], acc[mh * 2 + mt2][nh * 2 + nt2],
              0, 0, 0);
    __builtin_amdgcn_s_setprio(0);
  };

  // prologue: tile 0, first-needed order A0,B0,B1,A1 (queue = 6)
  STAGE_A(0, 0); STAGE_B(0, 0); STAGE_B(1, 0); STAGE_A(1, 0);
  CFENCE();

  for (int t = 0; t < 31; ++t) {
    const char* Ab = smem + (t & 1) * 32768;
    const char* Bb = smem + 65536 + (t & 1) * 16384;
    const int nx = t + 1;
    // P1: needs A0(2)+B0(1) of t -> leave B1,A1(2) = vmcnt(3)
    __builtin_amdgcn_s_waitcnt(WAIT_VM3); CFENCE();
    __builtin_amdgcn_s_barrier(); CFENCE();
    read_a(Ab, 0); read_b(Bb, 0);
    STAGE_A(0, nx); CFENCE();
    do_mfma(0, 0);
    // P2: needs B1 of t -> leave A1(2)+A0'(2) = vmcnt(4)
    __builtin_amdgcn_s_waitcnt(WAIT_VM4); CFENCE();
    __builtin_amdgcn_s_barrier(); CFENCE();
    read_b(Bb, 1);
    STAGE_B(0, nx); CFENCE();
    do_mfma(0, 1);
    // P3: needs A1(2) of t -> leave A0'(2)+B0'(1) = vmcnt(3)
    __builtin_amdgcn_s_waitcnt(WAIT_VM3); CFENCE();
    __builtin_amdgcn_s_barrier(); CFENCE();
    read_a(Ab, 1);
    STAGE_B(1, nx); CFENCE();
    do_mfma(1, 0);
    // P4: all in registers
    __builtin_amdgcn_s_barrier(); CFENCE();
    STAGE_A(1, nx); CFENCE();
    do_mfma(1, 1);
  }
  {  // peeled last tile (t=31, buf1): drain 3 -> 2 -> 0
    const char* Ab = smem + 32768;
    const char* Bb = smem + 65536 + 16384;
    __builtin_amdgcn_s_waitcnt(WAIT_VM3); CFENCE();
    __builtin_amdgcn_s_barrier(); CFENCE();
    read_a(Ab, 0); read_b(Bb, 0);
    do_mfma(0, 0);
    __builtin_amdgcn_s_waitcnt(WAIT_VM2); CFENCE();
    __builtin_amdgcn_s_barrier(); CFENCE();
    read_b(Bb, 1);
    do_mfma(0, 1);
    __builtin_amdgcn_s_waitcnt(WAIT_VM0); CFENCE();
    __builtin_amdgcn_s_barrier(); CFENCE();
    read_a(Ab, 1);
    do_mfma(1, 0);
    do_mfma(1, 1);
  }
#undef STAGE_A
#undef STAGE_B

#pragma unroll
  for (int mt = 0; mt < 4; ++mt)
#pragma unroll
    for (int nt = 0; nt < 4; ++nt)
#pragma unroll
      for (int r = 0; r < 4; ++r) {
        const int row = m0 + wm * 64 + mt * 16 + quad * 4 + r;
        const int col = n0 + wn * 64 + nt * 16 + l16;
        C[(size_t)row * 2048 + col] = acc[mt][nt][r];
      }
}

// ---------------- fused QKV GEMM: 256x192 tile, 256 blocks = 1/CU -----------
// Wave grid 4(M)x2(N); wave wn owns interleaved 16-col chunks {wn, wn+2} of
// each 64-col block so RoPE pairs (d, d+32) stay in-wave. 4-phase counted-
// vmcnt schedule (T3/T4), st_16x32 swizzle (T2), setprio (T5), bijective XCD
// swizzle over 256 = 8x32 (T1). Stage 7 units/wave/tile in first-needed
// order A0(2),B0(1),B12(2),A1(2): waits vm4/vm4/vm3/none; drain in peel.
__global__ __launch_bounds__(512, 2)
void gemm_qkv9(const bf16* __restrict__ A, const bf16* __restrict__ Wq,
               const bf16* __restrict__ Wk, const bf16* __restrict__ Wv,
               bf16* __restrict__ Qo, bf16* __restrict__ Ko,
               bf16* __restrict__ Vt) {
  __shared__ __align__(16) char smem[114688];  // A[2]: 0/32K, B[2]: 64K/88K
  const int tid  = threadIdx.x;
  const int wave = tid >> 6, lane = tid & 63;
  const int quad = lane >> 4, l16 = lane & 15;
  const int wm = wave >> 1, wn = wave & 1;   // 4x2 wave grid, 64 rows x 96 cols

  // XCD-swizzled tile coords (grid 16x16 = 256 = 8 XCD x 32, bijective)
  const int flat = blockIdx.y * 16 + blockIdx.x;
  const int swz  = (flat & 7) * 32 + (flat >> 3);
  const int m0 = (swz >> 4) * 256;
  const int n0 = (swz & 15) * 192;

  // swizzled within-subtile read byte offset (st_16x32, R6-verified formulas)
  const int rdb = (l16 * 64 + quad * 16) ^ ((l16 & 8) << 2);

  // ---- stage source (pre-swizzled global col) + LDS dest, per unit ----
  const int srow = lane >> 2;
  const int scol = ((lane & 3) * 8) ^ ((lane >> 5) << 4);

  // A: 32 units (16-row block rb x k-half), 4/wave. P1 region rb mod 4 in
  // {0,1}; P3 region rb mod 4 in {2,3}.
  const int rbA0 = (wave >> 1) * 4 + (wave & 1);
  const int rbA1 = rbA0 + 2;
  const bf16* a0p = A + (size_t)(m0 + rbA0 * 16 + srow) * 2048 + scol;
  const bf16* a1p = A + (size_t)(m0 + rbA1 * 16 + srow) * 2048 + scol;
  const int da0 = (rbA0 * 2) << 10;
  const int da1 = (rbA1 * 2) << 10;

  // B: 24 units (12 row-blocks x 2 k-halves), 3/wave. P1 region = rows 0-63
  // (8 units, 1/wave); P2 region = rows 64-191 (16 units, 2/wave). 16-row
  // blocks never straddle the Q|K|V boundaries (2048/2560 are 16-aligned).
  const int rbB0 = wave >> 1, khB0 = wave & 1;
  const int rbB1 = 4 + wave;
  const int nrow0 = n0 + rbB0 * 16 + srow;
  const int nrow1 = n0 + rbB1 * 16 + srow;
  const bf16* b0p = (nrow0 < 2048 ? Wq + (size_t)nrow0 * 2048
                   : nrow0 < 2560 ? Wk + (size_t)(nrow0 - 2048) * 2048
                                  : Wv + (size_t)(nrow0 - 2560) * 2048)
                    + scol + khB0 * 32;
  const bf16* b1p = (nrow1 < 2048 ? Wq + (size_t)nrow1 * 2048
                   : nrow1 < 2560 ? Wk + (size_t)(nrow1 - 2048) * 2048
                                  : Wv + (size_t)(nrow1 - 2560) * 2048)
                    + scol;
  const int db0 = (rbB0 * 2 + khB0) << 10;
  const int db1 = (rbB1 * 2) << 10;

#define STAGE_A0(tt) do { char* _b = smem + ((tt) & 1) * 32768;        \
    async_copy16(a0p + (tt) * 64,      _b + da0);                      \
    async_copy16(a0p + (tt) * 64 + 32, _b + da0 + 1024); } while (0)
#define STAGE_A1(tt) do { char* _b = smem + ((tt) & 1) * 32768;        \
    async_copy16(a1p + (tt) * 64,      _b + da1);                      \
    async_copy16(a1p + (tt) * 64 + 32, _b + da1 + 1024); } while (0)
#define STAGE_B0(tt) do { char* _b = smem + 65536 + ((tt) & 1) * 24576; \
    async_copy16(b0p + (tt) * 64,      _b + db0); } while (0)
#define STAGE_B12(tt) do { char* _b = smem + 65536 + ((tt) & 1) * 24576; \
    async_copy16(b1p + (tt) * 64,      _b + db1);                      \
    async_copy16(b1p + (tt) * 64 + 32, _b + db1 + 1024); } while (0)

  f32x4 acc[4][6];
#pragma unroll
  for (int i = 0; i < 4; ++i)
#pragma unroll
    for (int j = 0; j < 6; ++j) acc[i][j] = (f32x4){0.f, 0.f, 0.f, 0.f};

  bf16x8 afr[2][2];   // current mt-pair (mh half)
  bf16x8 bfr[6][2];   // all 6 interleaved n-chunks, held across K-tile

  auto read_a = [&](const char* Ab, int mh) __attribute__((always_inline)) {
#pragma unroll
    for (int mt2 = 0; mt2 < 2; ++mt2)
#pragma unroll
      for (int ks = 0; ks < 2; ++ks)
        afr[mt2][ks] = *(const bf16x8*)(
            Ab + (((wm * 4 + mh * 2 + mt2) * 2 + ks) << 10) + rdb);
  };
  // chunk index of frag j: cc = (j>>1)*4 + (j&1)*2 + wn
  auto read_b = [&](const char* Bb, int jlo, int jhi) __attribute__((always_inline)) {
#pragma unroll
    for (int j = 0; j < 6; ++j) {
      if (j < jlo || j > jhi) continue;
      const int cc = (j >> 1) * 4 + (j & 1) * 2 + wn;
#pragma unroll
      for (int ks = 0; ks < 2; ++ks)
        bfr[j][ks] = *(const bf16x8*)(Bb + ((cc * 2 + ks) << 10) + rdb);
    }
  };
  auto do_mfma = [&](int mh, int jlo, int jhi) __attribute__((always_inline)) {
    __builtin_amdgcn_s_setprio(1);
#pragma unroll
    for (int mt2 = 0; mt2 < 2; ++mt2)
#pragma unroll
      for (int j = 0; j < 6; ++j) {
        if (j < jlo || j > jhi) continue;
#pragma unroll
        for (int ks = 0; ks < 2; ++ks)
          acc[mh * 2 + mt2][j] = __builtin_amdgcn_mfma_f32_16x16x32_bf16(
              afr[mt2][ks], bfr[j][ks], acc[mh * 2 + mt2][j], 0, 0, 0);
      }
    __builtin_amdgcn_s_setprio(0);
  };

  // prologue: tile 0, first-needed order
  STAGE_A0(0); STAGE_B0(0); STAGE_B12(0); STAGE_A1(0);
  CFENCE();

  for (int t = 0; t < 31; ++t) {
    const char* Ab = smem + (t & 1) * 32768;
    const char* Bb = smem + 65536 + (t & 1) * 24576;
    const int nx = t + 1;
    // P1: needs A0,B0 of t (first 3 of 7) -> vmcnt(4)
    __builtin_amdgcn_s_waitcnt(WAIT_VM4); CFENCE();
    __builtin_amdgcn_s_barrier(); CFENCE();
    read_a(Ab, 0); read_b(Bb, 0, 1);
    STAGE_A0(nx); CFENCE();
    do_mfma(0, 0, 1);
    // P2: needs B12 of t -> leave A1(t)+A0(t+1) = vmcnt(4)
    __builtin_amdgcn_s_waitcnt(WAIT_VM4); CFENCE();
    __builtin_amdgcn_s_barrier(); CFENCE();
    read_b(Bb, 2, 5);
    STAGE_B0(nx); CFENCE();
    do_mfma(0, 2, 5);
    // P3: needs A1 of t -> leave A0(2)+B0(1) of t+1 = vmcnt(3)
    __builtin_amdgcn_s_waitcnt(WAIT_VM3); CFENCE();
    __builtin_amdgcn_s_barrier(); CFENCE();
    read_a(Ab, 1);
    STAGE_B12(nx); CFENCE();
    do_mfma(1, 0, 1);
    // P4: all in registers
    __builtin_amdgcn_s_barrier(); CFENCE();
    STAGE_A1(nx); CFENCE();
    do_mfma(1, 2, 5);
  }
  {  // peeled last tile (t=31, buf1): drain 4 -> 2 -> 0
    const char* Ab = smem + 32768;
    const char* Bb = smem + 65536 + 24576;
    __builtin_amdgcn_s_waitcnt(WAIT_VM4); CFENCE();
    __builtin_amdgcn_s_barrier(); CFENCE();
    read_a(Ab, 0); read_b(Bb, 0, 1);
    do_mfma(0, 0, 1);
    __builtin_amdgcn_s_waitcnt(WAIT_VM2); CFENCE();
    __builtin_amdgcn_s_barrier(); CFENCE();
    read_b(Bb, 2, 5);
    do_mfma(0, 2, 5);
    __builtin_amdgcn_s_waitcnt(WAIT_VM0); CFENCE();
    __builtin_amdgcn_s_barrier(); CFENCE();
    read_a(Ab, 1);
    do_mfma(1, 0, 1);
    do_mfma(1, 2, 5);
  }
#undef STAGE_A0
#undef STAGE_A1
#undef STAGE_B0
#undef STAGE_B12

  // epilogue: RoPE on rotary 64-blocks (cb ≡ 0 mod 128, cb < 2560).
  // frag 2b holds col cb + d, frag 2b+1 holds col cb + d + 32, d = wn*16+l16.
  {
    const float d = (float)(wn * 16 + l16);
    const float invf = exp2f(-d * 0.41524101186091903f);  // 1e4^(-d/32)
#pragma unroll
    for (int b = 0; b < 3; ++b) {
      const int cb = n0 + b * 64;
      if (cb < 2560 && (cb & 127) == 0) {
#pragma unroll
        for (int mt = 0; mt < 4; ++mt)
#pragma unroll
          for (int r = 0; r < 4; ++r) {
            const int pos = (m0 + wm * 64 + mt * 16 + quad * 4 + r) & (S_LEN - 1);
            float s, c;
            __sincosf((float)pos * invf, &s, &c);
            const float x1 = acc[mt][2 * b][r], x2 = acc[mt][2 * b + 1][r];
            acc[mt][2 * b][r]     = x1 * c - x2 * s;
            acc[mt][2 * b + 1][r] = x2 * c + x1 * s;
          }
      }
    }
  }
#pragma unroll
  for (int mt = 0; mt < 4; ++mt) {
    const int row0 = m0 + wm * 64 + mt * 16 + quad * 4;
#pragma unroll
    for (int j = 0; j < 6; ++j) {
      const int col16 = n0 + (j >> 1) * 64 + ((j & 1) * 2 + wn) * 16;
      if (col16 < 2048) {                 // Q: [tok][2048]
#pragma unroll
        for (int r = 0; r < 4; ++r)
          Qo[(size_t)(row0 + r) * 2048 + col16 + l16] = (bf16)acc[mt][j][r];
      } else if (col16 < 2560) {          // K: [tok][512]
#pragma unroll
        for (int r = 0; r < 4; ++r)
          Ko[(size_t)(row0 + r) * 512 + col16 - 2048 + l16] = (bf16)acc[mt][j][r];
      } else {                            // V: transposed vt[(b*4+kv)*128+d][s]
        const int colv = col16 + l16 - 2560;
        const int bb = row0 >> 11, s0 = row0 & (S_LEN - 1);
        bf16x4 tq = {(bf16)acc[mt][j][0], (bf16)acc[mt][j][1],
                     (bf16)acc[mt][j][2], (bf16)acc[mt][j][3]};
        *(bf16x4*)(Vt + ((size_t)(bb * NH_KV + (colv >> 7)) * HD_ + (colv & 127))
                        * S_LEN + s0) = tq;
      }
    }
  }
}

// ---------------- flash attention, S^T formulation --------------------------
#define KS_STRIDE 136   // 64 keys x 128 d, +8 pad (2-way banks = free)
#define VT_STRIDE 72    // 128 d x 64 keys, +8 pad

__global__ __launch_bounds__(256)
void attn_kernel(const bf16* __restrict__ Qg, const bf16* __restrict__ Kg,
                 const bf16* __restrict__ Vtg, bf16* __restrict__ Og) {
  __shared__ __align__(16) bf16 Ks[64 * KS_STRIDE];   // K tile [key][d]
  __shared__ __align__(16) bf16 Vt[128 * VT_STRIDE];  // V^T tile [d][key]
#if !HAVE_MFMA16
  __shared__ __align__(16) bf16 Pb[4][16 * 72];
#endif
  const int tid  = threadIdx.x;
  const int wave = tid >> 6, lane = tid & 63;
  const int quad = lane >> 4, l16 = lane & 15;
  const int qt = blockIdx.x, h = blockIdx.y, b = blockIdx.z;
  const int kv = h >> 2;
  const int q0 = qt * 64;
  const int tok0 = b * S_LEN;
  const float scale = 0.08838834764831845f;  // 1/sqrt(128)
  const int q = q0 + wave * 16 + l16;

  bf16x8 qf[4];
  {
    const bf16* qp = Qg + (size_t)(tok0 + q) * (NH_Q * HD_) + h * HD_ + quad * 8;
#pragma unroll
    for (int kb = 0; kb < 4; ++kb) qf[kb] = *(const bf16x8*)(qp + kb * 32);
  }

  f32x4 o[8];
#pragma unroll
  for (int dt = 0; dt < 8; ++dt) o[dt] = (f32x4){0.f, 0.f, 0.f, 0.f};
  float m_run = -__builtin_inff(), l_run = 0.f;

  int kt_begin = q0 - WIN;
  if (kt_begin < 0) kt_begin = 0;
  const int kt_end = q0 + 64;
  const bf16* vt_base = Vtg + (size_t)(b * NH_KV + kv) * HD_ * S_LEN;

  for (int kt = kt_begin; kt < kt_end; kt += 64) {
    __syncthreads();
#pragma unroll
    for (int it = 0; it < 4; ++it) {
      int vid = tid + it * 256;
      int key = vid >> 4, dblk = vid & 15;
      bf16x8 v = *(const bf16x8*)(Kg + (size_t)(tok0 + kt + key) * (NH_KV * HD_)
                                  + kv * HD_ + dblk * 8);
      *(bf16x8*)&Ks[key * KS_STRIDE + dblk * 8] = v;
    }
#pragma unroll
    for (int it = 0; it < 4; ++it) {
      int vid = tid + it * 256;
      int d = vid >> 3, kblk = vid & 7;
      bf16x8 v = *(const bf16x8*)(vt_base + (size_t)d * S_LEN + kt + kblk * 8);
      *(bf16x8*)&Vt[d * VT_STRIDE + kblk * 8] = v;
    }
    __syncthreads();

    f32x4 st[4];
#pragma unroll
    for (int nt = 0; nt < 4; ++nt) {
      f32x4 acc = (f32x4){0.f, 0.f, 0.f, 0.f};
#pragma unroll
      for (int kb = 0; kb < 4; ++kb) {
        bf16x8 kf = *(const bf16x8*)&Ks[(nt * 16 + l16) * KS_STRIDE + kb * 32 + quad * 8];
        acc = __builtin_amdgcn_mfma_f32_16x16x32_bf16(kf, qf[kb], acc, 0, 0, 0);
      }
      st[nt] = acc;
    }
#pragma unroll
    for (int nt = 0; nt < 4; ++nt)
#pragma unroll
      for (int r = 0; r < 4; ++r) {
        int key = kt + nt * 16 + quad * 4 + r;
        bool ok = (key <= q) && (key > q - WIN);
        st[nt][r] = ok ? st[nt][r] * scale : -__builtin_inff();
      }
    float mx = -__builtin_inff();
#pragma unroll
    for (int nt = 0; nt < 4; ++nt)
#pragma unroll
      for (int r = 0; r < 4; ++r) mx = fmaxf(mx, st[nt][r]);
    mx = fmaxf(mx, __shfl_xor(mx, 16, 64));
    mx = fmaxf(mx, __shfl_xor(mx, 32, 64));
    float mnew = fmaxf(m_run, mx);
    float msub = (mnew == -__builtin_inff()) ? 0.f : mnew;
    float alpha = __expf(m_run - msub);
    m_run = mnew;
    float p[4][4], psum = 0.f;
#pragma unroll
    for (int nt = 0; nt < 4; ++nt)
#pragma unroll
      for (int r = 0; r < 4; ++r) {
        p[nt][r] = __expf(st[nt][r] - msub);
        psum += p[nt][r];
      }
    psum += __shfl_xor(psum, 16, 64);
    psum += __shfl_xor(psum, 32, 64);
    l_run = l_run * alpha + psum;
#pragma unroll
    for (int dt = 0; dt < 8; ++dt) o[dt] *= alpha;

#if HAVE_MFMA16
    s16x4 pb[4];
#pragma unroll
    for (int nt = 0; nt < 4; ++nt)
#pragma unroll
      for (int r = 0; r < 4; ++r) {
        union { __bf16 h; short s; } u;
        u.h = (bf16)p[nt][r];
        pb[nt][r] = u.s;
      }
#pragma unroll
    for (int dt = 0; dt < 8; ++dt)
#pragma unroll
      for (int nt = 0; nt < 4; ++nt) {
        s16x4 vf = *(const s16x4*)&Vt[(dt * 16 + l16) * VT_STRIDE + nt * 16 + quad * 4];
        o[dt] = __builtin_amdgcn_mfma_f32_16x16x16bf16_1k(vf, pb[nt], o[dt], 0, 0, 0);
      }
#else
#pragma unroll
    for (int nt = 0; nt < 4; ++nt) {
      bf16x4 t;
#pragma unroll
      for (int r = 0; r < 4; ++r) t[r] = (bf16)p[nt][r];
      *(bf16x4*)&Pb[wave][l16 * 72 + nt * 16 + quad * 4] = t;
    }
    __syncthreads();
    bf16x8 pf[2];
    pf[0] = *(const bf16x8*)&Pb[wave][l16 * 72 + quad * 8];
    pf[1] = *(const bf16x8*)&Pb[wave][l16 * 72 + 32 + quad * 8];
#pragma unroll
    for (int dt = 0; dt < 8; ++dt)
#pragma unroll
      for (int kb = 0; kb < 2; ++kb) {
        bf16x8 vf = *(const bf16x8*)&Vt[(dt * 16 + l16) * VT_STRIDE + kb * 32 + quad * 8];
        o[dt] = __builtin_amdgcn_mfma_f32_16x16x32_bf16(vf, pf[kb], o[dt], 0, 0, 0);
      }
#endif
  }

  float inv = 1.f / l_run;
  __syncthreads();
#pragma unroll
  for (int dt = 0; dt < 8; ++dt) {
    bf16x4 t;
#pragma unroll
    for (int r = 0; r < 4; ++r) t[r] = (bf16)(o[dt][r] * inv);
    *(bf16x4*)&Ks[(wave * 16 + l16) * KS_STRIDE + dt * 16 + quad * 4] = t;
  }
  __syncthreads();
#pragma unroll
  for (int it = 0; it < 4; ++it) {
    int idx = tid + it * 256;
    int row = idx >> 4, chunk = idx & 15;
    bf16x8 v = *(const bf16x8*)&Ks[row * KS_STRIDE + chunk * 8];
    *(bf16x8*)(Og + (size_t)(tok0 + q0 + row) * (NH_Q * HD_) + h * HD_ + chunk * 8) = v;
  }
}

// ---------------- launcher ----------------
extern "C" void kernel_launch(void* const* d_in, const int* in_sizes, int n_in,
                              void* d_out, int out_size, void* d_ws, size_t ws_size,
                              hipStream_t stream) {
  const float* hs = (const float*)d_in[0];
  const float* Wq = (const float*)d_in[1];
  const float* Wk = (const float*)d_in[2];
  const float* Wv = (const float*)d_in[3];
  const float* Wo = (const float*)d_in[4];
  float* out = (float*)d_out;

  char* w = (char*)d_ws;
  bf16* hsb = (bf16*)w; w += (size_t)NTOK * 2048 * 2;   // 16.8 MB
  bf16* wqb = (bf16*)w; w += (size_t)2048 * 2048 * 2;   //  8.4 MB
  bf16* wkb = (bf16*)w; w += (size_t)512 * 2048 * 2;    //  2.1 MB
  bf16* wvb = (bf16*)w; w += (size_t)512 * 2048 * 2;    //  2.1 MB
  bf16* wob = (bf16*)w; w += (size_t)2048 * 2048 * 2;   //  8.4 MB
  bf16* qb  = (bf16*)w; w += (size_t)NTOK * 2048 * 2;   // 16.8 MB
  bf16* kb  = (bf16*)w; w += (size_t)NTOK * 512 * 2;    //  4.2 MB
  bf16* vtb = (bf16*)w; w += (size_t)NTOK * 512 * 2;    //  4.2 MB
  bf16* ab  = hsb;  // alias: hs_bf16 dead after QKV GEMM

  cvt_all<<<18874368 / 1024, 256, 0, stream>>>(hs, Wq, Wk, Wv, Wo,
                                               hsb, wqb, wkb, wvb, wob);

  gemm_qkv9<<<dim3(16, 16), 512, 0, stream>>>(hsb, wqb, wkb, wvb,
                                              qb, kb, vtb);

  attn_kernel<<<dim3(S_LEN / 64, NH_Q, 2), 256, 0, stream>>>(qb, kb, vtb, ab);

  gemm_out8<<<dim3(16, 16), 512, 0, stream>>>(ab, wob, out);
}

// Round 4
// 233.659 us; speedup vs baseline: 1.1862x; 1.0452x over previous
//
#include <hip/hip_runtime.h>
#include <cstdint>
#include <cstddef>

typedef __bf16 bf16;
typedef __attribute__((ext_vector_type(8))) __bf16 bf16x8;
typedef __attribute__((ext_vector_type(4))) __bf16 bf16x4;
typedef __attribute__((ext_vector_type(4))) float f32x4;
typedef __attribute__((ext_vector_type(4))) short s16x4;

#define S_LEN   2048
#define WIN     512
#define NH_Q    16
#define NH_KV   4
#define HD_     128
#define NTOK    4096   // B * S

// Q is pre-scaled by (1/sqrt(128)) * log2(e) at the QKV epilogue, so attn
// uses exp2 directly and needs no per-score scale multiply.
#define QSCALE_LOG2E 0.12751744561823337f

#if defined(__has_builtin)
#if __has_builtin(__builtin_amdgcn_mfma_f32_16x16x16bf16_1k)
#define HAVE_MFMA16 1
#endif
#endif
#ifndef HAVE_MFMA16
#define HAVE_MFMA16 0
#endif

// s_waitcnt immediates (gfx9 encoding: vm[3:0]=s[3:0], exp=s[6:4],
// lgkm=s[11:8], vm[5:4]=s[15:14]); non-waited fields all-ones.
#define WAIT_VM4   0x0F74  // vmcnt<=4
#define WAIT_VM3   0x0F73  // vmcnt<=3
#define WAIT_VM2   0x0F72  // vmcnt<=2
#define WAIT_VM0   0x0F70  // vmcnt<=0
#define CFENCE() __asm__ __volatile__("" ::: "memory")

// async global->LDS, 16B per lane; LDS dest = wave-uniform base + lane*16
__device__ __forceinline__ void async_copy16(const void* g, void* l) {
  __builtin_amdgcn_global_load_lds(
      (const __attribute__((address_space(1))) void*)g,
      (__attribute__((address_space(3))) void*)l, 16, 0, 0);
}

// ---------------- fp32 -> bf16 convert, all 5 arrays in one launch ----------
__global__ __launch_bounds__(256)
void cvt_all(const float* __restrict__ hs, const float* __restrict__ wq,
             const float* __restrict__ wk, const float* __restrict__ wv,
             const float* __restrict__ wo, bf16* __restrict__ hsb,
             bf16* __restrict__ wqb, bf16* __restrict__ wkb,
             bf16* __restrict__ wvb, bf16* __restrict__ wob) {
  long i = ((long)blockIdx.x * 256 + threadIdx.x) * 4;  // < 18874368
  const float* in;
  bf16* out;
  if (i < 8388608)       { in = hs + i;            out = hsb + i; }
  else if (i < 12582912) { in = wq + (i - 8388608); out = wqb + (i - 8388608); }
  else if (i < 13631488) { in = wk + (i - 12582912); out = wkb + (i - 12582912); }
  else if (i < 14680064) { in = wv + (i - 13631488); out = wvb + (i - 13631488); }
  else                   { in = wo + (i - 14680064); out = wob + (i - 14680064); }
  float4 v = *(const float4*)in;
  bf16x4 t = {(bf16)v.x, (bf16)v.y, (bf16)v.z, (bf16)v.w};
  *(bf16x4*)out = t;
}

// ---------------- output GEMM: 256x128 tile, 4-phase schedule, 1 block/CU ---
__global__ __launch_bounds__(512, 2)
void gemm_out8(const bf16* __restrict__ A, const bf16* __restrict__ W,
               float* __restrict__ C) {
  __shared__ __align__(16) char smem[98304];  // A[2]: 0/32K, B[2]: 64K/80K
  const int tid  = threadIdx.x;
  const int wave = tid >> 6, lane = tid & 63;
  const int quad = lane >> 4, l16 = lane & 15;
  const int wm = wave >> 1, wn = wave & 1;   // 4x2 wave grid, 64x64 each

  // XCD-swizzled tile coords (grid 16(n) x 16(m) = 256 = 8 XCD x 32)
  const int flat = blockIdx.y * 16 + blockIdx.x;
  const int swz  = (flat & 7) * 32 + (flat >> 3);
  const int m0 = (swz >> 4) * 256;
  const int n0 = (swz & 15) * 128;

  // swizzled within-subtile read byte offset (st_16x32, R6-verified)
  const int rdb = (l16 * 64 + quad * 16) ^ ((l16 & 8) << 2);
  const int srow = lane >> 2;
  const int scol = ((lane & 3) * 8) ^ ((lane >> 5) << 4);

  const bf16* aptr[2][2];
  int adst[2][2];
#pragma unroll
  for (int mh = 0; mh < 2; ++mh)
#pragma unroll
    for (int j = 0; j < 2; ++j) {
      const int rb = (wave >> 1) * 4 + mh * 2 + j;
      aptr[mh][j] = A + (size_t)(m0 + rb * 16 + srow) * 2048 + scol
                    + (wave & 1) * 32;
      adst[mh][j] = (rb * 2 + (wave & 1)) << 10;
    }
  const bf16* bptr[2];
  int bdst[2];
#pragma unroll
  for (int nh = 0; nh < 2; ++nh) {
    const int cb = (wave >> 2) * 4 + nh * 2 + ((wave >> 1) & 1);
    bptr[nh] = W + (size_t)(n0 + cb * 16 + srow) * 2048 + scol
               + (wave & 1) * 32;
    bdst[nh] = (cb * 2 + (wave & 1)) << 10;
  }

#define STAGE_A(mh, tt) do { char* _b = smem + ((tt) & 1) * 32768;      \
    async_copy16(aptr[mh][0] + (tt) * 64, _b + adst[mh][0]);            \
    async_copy16(aptr[mh][1] + (tt) * 64, _b + adst[mh][1]); } while (0)
#define STAGE_B(nh, tt) do { char* _b = smem + 65536 + ((tt) & 1) * 16384; \
    async_copy16(bptr[nh] + (tt) * 64, _b + bdst[nh]); } while (0)

  f32x4 acc[4][4];
#pragma unroll
  for (int i = 0; i < 4; ++i)
#pragma unroll
    for (int j = 0; j < 4; ++j) acc[i][j] = (f32x4){0.f, 0.f, 0.f, 0.f};

  bf16x8 afr[2][2];
  bf16x8 bfr[2][2][2];

  auto read_a = [&](const char* Ab, int mh) __attribute__((always_inline)) {
#pragma unroll
    for (int mt2 = 0; mt2 < 2; ++mt2)
#pragma unroll
      for (int ks = 0; ks < 2; ++ks)
        afr[mt2][ks] = *(const bf16x8*)(
            Ab + (((wm * 4 + mh * 2 + mt2) * 2 + ks) << 10) + rdb);
  };
  auto read_b = [&](const char* Bb, int nh) __attribute__((always_inline)) {
#pragma unroll
    for (int nt2 = 0; nt2 < 2; ++nt2)
#pragma unroll
      for (int ks = 0; ks < 2; ++ks)
        bfr[nh][nt2][ks] = *(const bf16x8*)(
            Bb + (((wn * 4 + nh * 2 + nt2) * 2 + ks) << 10) + rdb);
  };
  auto do_mfma = [&](int mh, int nh) __attribute__((always_inline)) {
    __builtin_amdgcn_s_setprio(1);
#pragma unroll
    for (int mt2 = 0; mt2 < 2; ++mt2)
#pragma unroll
      for (int nt2 = 0; nt2 < 2; ++nt2)
#pragma unroll
        for (int ks = 0; ks < 2; ++ks)
          acc[mh * 2 + mt2][nh * 2 + nt2] = __builtin_amdgcn_mfma_f32_16x16x32_bf16(
              afr[mt2][ks], bfr[nh][nt2][ks], acc[mh * 2 + mt2][nh * 2 + nt2],
              0, 0, 0);
    __builtin_amdgcn_s_setprio(0);
  };

  STAGE_A(0, 0); STAGE_B(0, 0); STAGE_B(1, 0); STAGE_A(1, 0);
  CFENCE();

  for (int t = 0; t < 31; ++t) {
    const char* Ab = smem + (t & 1) * 32768;
    const char* Bb = smem + 65536 + (t & 1) * 16384;
    const int nx = t + 1;
    __builtin_amdgcn_s_waitcnt(WAIT_VM3); CFENCE();
    __builtin_amdgcn_s_barrier(); CFENCE();
    read_a(Ab, 0); read_b(Bb, 0);
    STAGE_A(0, nx); CFENCE();
    do_mfma(0, 0);
    __builtin_amdgcn_s_waitcnt(WAIT_VM4); CFENCE();
    __builtin_amdgcn_s_barrier(); CFENCE();
    read_b(Bb, 1);
    STAGE_B(0, nx); CFENCE();
    do_mfma(0, 1);
    __builtin_amdgcn_s_waitcnt(WAIT_VM3); CFENCE();
    __builtin_amdgcn_s_barrier(); CFENCE();
    read_a(Ab, 1);
    STAGE_B(1, nx); CFENCE();
    do_mfma(1, 0);
    __builtin_amdgcn_s_barrier(); CFENCE();
    STAGE_A(1, nx); CFENCE();
    do_mfma(1, 1);
  }
  {
    const char* Ab = smem + 32768;
    const char* Bb = smem + 65536 + 16384;
    __builtin_amdgcn_s_waitcnt(WAIT_VM3); CFENCE();
    __builtin_amdgcn_s_barrier(); CFENCE();
    read_a(Ab, 0); read_b(Bb, 0);
    do_mfma(0, 0);
    __builtin_amdgcn_s_waitcnt(WAIT_VM2); CFENCE();
    __builtin_amdgcn_s_barrier(); CFENCE();
    read_b(Bb, 1);
    do_mfma(0, 1);
    __builtin_amdgcn_s_waitcnt(WAIT_VM0); CFENCE();
    __builtin_amdgcn_s_barrier(); CFENCE();
    read_a(Ab, 1);
    do_mfma(1, 0);
    do_mfma(1, 1);
  }
#undef STAGE_A
#undef STAGE_B

#pragma unroll
  for (int mt = 0; mt < 4; ++mt)
#pragma unroll
    for (int nt = 0; nt < 4; ++nt)
#pragma unroll
      for (int r = 0; r < 4; ++r) {
        const int row = m0 + wm * 64 + mt * 16 + quad * 4 + r;
        const int col = n0 + wn * 64 + nt * 16 + l16;
        C[(size_t)row * 2048 + col] = acc[mt][nt][r];
      }
}

// ---------------- fused QKV GEMM: 256x192 tile, 256 blocks = 1/CU -----------
// Q-region stores are pre-scaled by QSCALE_LOG2E (commutes with RoPE).
__global__ __launch_bounds__(512, 2)
void gemm_qkv9(const bf16* __restrict__ A, const bf16* __restrict__ Wq,
               const bf16* __restrict__ Wk, const bf16* __restrict__ Wv,
               bf16* __restrict__ Qo, bf16* __restrict__ Ko,
               bf16* __restrict__ Vt) {
  __shared__ __align__(16) char smem[114688];  // A[2]: 0/32K, B[2]: 64K/88K
  const int tid  = threadIdx.x;
  const int wave = tid >> 6, lane = tid & 63;
  const int quad = lane >> 4, l16 = lane & 15;
  const int wm = wave >> 1, wn = wave & 1;   // 4x2 wave grid, 64 rows x 96 cols

  const int flat = blockIdx.y * 16 + blockIdx.x;
  const int swz  = (flat & 7) * 32 + (flat >> 3);
  const int m0 = (swz >> 4) * 256;
  const int n0 = (swz & 15) * 192;

  const int rdb = (l16 * 64 + quad * 16) ^ ((l16 & 8) << 2);
  const int srow = lane >> 2;
  const int scol = ((lane & 3) * 8) ^ ((lane >> 5) << 4);

  const int rbA0 = (wave >> 1) * 4 + (wave & 1);
  const int rbA1 = rbA0 + 2;
  const bf16* a0p = A + (size_t)(m0 + rbA0 * 16 + srow) * 2048 + scol;
  const bf16* a1p = A + (size_t)(m0 + rbA1 * 16 + srow) * 2048 + scol;
  const int da0 = (rbA0 * 2) << 10;
  const int da1 = (rbA1 * 2) << 10;

  const int rbB0 = wave >> 1, khB0 = wave & 1;
  const int rbB1 = 4 + wave;
  const int nrow0 = n0 + rbB0 * 16 + srow;
  const int nrow1 = n0 + rbB1 * 16 + srow;
  const bf16* b0p = (nrow0 < 2048 ? Wq + (size_t)nrow0 * 2048
                   : nrow0 < 2560 ? Wk + (size_t)(nrow0 - 2048) * 2048
                                  : Wv + (size_t)(nrow0 - 2560) * 2048)
                    + scol + khB0 * 32;
  const bf16* b1p = (nrow1 < 2048 ? Wq + (size_t)nrow1 * 2048
                   : nrow1 < 2560 ? Wk + (size_t)(nrow1 - 2048) * 2048
                                  : Wv + (size_t)(nrow1 - 2560) * 2048)
                    + scol;
  const int db0 = (rbB0 * 2 + khB0) << 10;
  const int db1 = (rbB1 * 2) << 10;

#define STAGE_A0(tt) do { char* _b = smem + ((tt) & 1) * 32768;        \
    async_copy16(a0p + (tt) * 64,      _b + da0);                      \
    async_copy16(a0p + (tt) * 64 + 32, _b + da0 + 1024); } while (0)
#define STAGE_A1(tt) do { char* _b = smem + ((tt) & 1) * 32768;        \
    async_copy16(a1p + (tt) * 64,      _b + da1);                      \
    async_copy16(a1p + (tt) * 64 + 32, _b + da1 + 1024); } while (0)
#define STAGE_B0(tt) do { char* _b = smem + 65536 + ((tt) & 1) * 24576; \
    async_copy16(b0p + (tt) * 64,      _b + db0); } while (0)
#define STAGE_B12(tt) do { char* _b = smem + 65536 + ((tt) & 1) * 24576; \
    async_copy16(b1p + (tt) * 64,      _b + db1);                      \
    async_copy16(b1p + (tt) * 64 + 32, _b + db1 + 1024); } while (0)

  f32x4 acc[4][6];
#pragma unroll
  for (int i = 0; i < 4; ++i)
#pragma unroll
    for (int j = 0; j < 6; ++j) acc[i][j] = (f32x4){0.f, 0.f, 0.f, 0.f};

  bf16x8 afr[2][2];
  bf16x8 bfr[6][2];

  auto read_a = [&](const char* Ab, int mh) __attribute__((always_inline)) {
#pragma unroll
    for (int mt2 = 0; mt2 < 2; ++mt2)
#pragma unroll
      for (int ks = 0; ks < 2; ++ks)
        afr[mt2][ks] = *(const bf16x8*)(
            Ab + (((wm * 4 + mh * 2 + mt2) * 2 + ks) << 10) + rdb);
  };
  auto read_b = [&](const char* Bb, int jlo, int jhi) __attribute__((always_inline)) {
#pragma unroll
    for (int j = 0; j < 6; ++j) {
      if (j < jlo || j > jhi) continue;
      const int cc = (j >> 1) * 4 + (j & 1) * 2 + wn;
#pragma unroll
      for (int ks = 0; ks < 2; ++ks)
        bfr[j][ks] = *(const bf16x8*)(Bb + ((cc * 2 + ks) << 10) + rdb);
    }
  };
  auto do_mfma = [&](int mh, int jlo, int jhi) __attribute__((always_inline)) {
    __builtin_amdgcn_s_setprio(1);
#pragma unroll
    for (int mt2 = 0; mt2 < 2; ++mt2)
#pragma unroll
      for (int j = 0; j < 6; ++j) {
        if (j < jlo || j > jhi) continue;
#pragma unroll
        for (int ks = 0; ks < 2; ++ks)
          acc[mh * 2 + mt2][j] = __builtin_amdgcn_mfma_f32_16x16x32_bf16(
              afr[mt2][ks], bfr[j][ks], acc[mh * 2 + mt2][j], 0, 0, 0);
      }
    __builtin_amdgcn_s_setprio(0);
  };

  STAGE_A0(0); STAGE_B0(0); STAGE_B12(0); STAGE_A1(0);
  CFENCE();

  for (int t = 0; t < 31; ++t) {
    const char* Ab = smem + (t & 1) * 32768;
    const char* Bb = smem + 65536 + (t & 1) * 24576;
    const int nx = t + 1;
    __builtin_amdgcn_s_waitcnt(WAIT_VM4); CFENCE();
    __builtin_amdgcn_s_barrier(); CFENCE();
    read_a(Ab, 0); read_b(Bb, 0, 1);
    STAGE_A0(nx); CFENCE();
    do_mfma(0, 0, 1);
    __builtin_amdgcn_s_waitcnt(WAIT_VM4); CFENCE();
    __builtin_amdgcn_s_barrier(); CFENCE();
    read_b(Bb, 2, 5);
    STAGE_B0(nx); CFENCE();
    do_mfma(0, 2, 5);
    __builtin_amdgcn_s_waitcnt(WAIT_VM3); CFENCE();
    __builtin_amdgcn_s_barrier(); CFENCE();
    read_a(Ab, 1);
    STAGE_B12(nx); CFENCE();
    do_mfma(1, 0, 1);
    __builtin_amdgcn_s_barrier(); CFENCE();
    STAGE_A1(nx); CFENCE();
    do_mfma(1, 2, 5);
  }
  {
    const char* Ab = smem + 32768;
    const char* Bb = smem + 65536 + 24576;
    __builtin_amdgcn_s_waitcnt(WAIT_VM4); CFENCE();
    __builtin_amdgcn_s_barrier(); CFENCE();
    read_a(Ab, 0); read_b(Bb, 0, 1);
    do_mfma(0, 0, 1);
    __builtin_amdgcn_s_waitcnt(WAIT_VM2); CFENCE();
    __builtin_amdgcn_s_barrier(); CFENCE();
    read_b(Bb, 2, 5);
    do_mfma(0, 2, 5);
    __builtin_amdgcn_s_waitcnt(WAIT_VM0); CFENCE();
    __builtin_amdgcn_s_barrier(); CFENCE();
    read_a(Ab, 1);
    do_mfma(1, 0, 1);
    do_mfma(1, 2, 5);
  }
#undef STAGE_A0
#undef STAGE_A1
#undef STAGE_B0
#undef STAGE_B12

  // epilogue: RoPE on rotary 64-blocks (cb ≡ 0 mod 128, cb < 2560).
  {
    const float d = (float)(wn * 16 + l16);
    const float invf = exp2f(-d * 0.41524101186091903f);  // 1e4^(-d/32)
#pragma unroll
    for (int b = 0; b < 3; ++b) {
      const int cb = n0 + b * 64;
      if (cb < 2560 && (cb & 127) == 0) {
#pragma unroll
        for (int mt = 0; mt < 4; ++mt)
#pragma unroll
          for (int r = 0; r < 4; ++r) {
            const int pos = (m0 + wm * 64 + mt * 16 + quad * 4 + r) & (S_LEN - 1);
            float s, c;
            __sincosf((float)pos * invf, &s, &c);
            const float x1 = acc[mt][2 * b][r], x2 = acc[mt][2 * b + 1][r];
            acc[mt][2 * b][r]     = x1 * c - x2 * s;
            acc[mt][2 * b + 1][r] = x2 * c + x1 * s;
          }
      }
    }
  }
#pragma unroll
  for (int mt = 0; mt < 4; ++mt) {
    const int row0 = m0 + wm * 64 + mt * 16 + quad * 4;
#pragma unroll
    for (int j = 0; j < 6; ++j) {
      const int col16 = n0 + (j >> 1) * 64 + ((j & 1) * 2 + wn) * 16;
      if (col16 < 2048) {                 // Q: [tok][2048], pre-scaled
#pragma unroll
        for (int r = 0; r < 4; ++r)
          Qo[(size_t)(row0 + r) * 2048 + col16 + l16] =
              (bf16)(acc[mt][j][r] * QSCALE_LOG2E);
      } else if (col16 < 2560) {          // K: [tok][512]
#pragma unroll
        for (int r = 0; r < 4; ++r)
          Ko[(size_t)(row0 + r) * 512 + col16 - 2048 + l16] = (bf16)acc[mt][j][r];
      } else {                            // V: transposed vt[(b*4+kv)*128+d][s]
        const int colv = col16 + l16 - 2560;
        const int bb = row0 >> 11, s0 = row0 & (S_LEN - 1);
        bf16x4 tq = {(bf16)acc[mt][j][0], (bf16)acc[mt][j][1],
                     (bf16)acc[mt][j][2], (bf16)acc[mt][j][3]};
        *(bf16x4*)(Vt + ((size_t)(bb * NH_KV + (colv >> 7)) * HD_ + (colv & 127))
                        * S_LEN + s0) = tq;
      }
    }
  }
}

// ---------------- flash attention v2: 128-query blocks, 8 waves -------------
// Round-3 counters (64q blocks): 54us, MfmaUtil 17.8, VALUBusy 37.9, Occ 20.5
// -- latency/VALU-bound (MFMA floor ~5.5us). Fixes: QBLK=128 halves staging
// bytes + barriers per query; T14 reg-prefetch of next K/V tile (issue after
// compute barrier, ds_write after next barrier) hides HBM/L2 latency under
// compute; T1 XCD swizzle (512 = 8 XCD x 64: each XCD gets exactly one
// (batch, kv-head) -> 1MB K+V, L2-resident); boundary-only masking (wave-
// uniform need_c/need_l; 7/9 tiles mask-free); T13 defer-max skips O-rescale;
// Q pre-scaled upstream so softmax is exp2-direct; T5 setprio around MFMA.
#define KS_STRIDE 136   // 64 keys x 128 d (+pad)
#define VT_STRIDE 72    // 128 d x 64 keys (+pad)

__global__ __launch_bounds__(512, 4)
void attn_kernel(const bf16* __restrict__ Qg, const bf16* __restrict__ Kg,
                 const bf16* __restrict__ Vtg, bf16* __restrict__ Og) {
  __shared__ __align__(16) char smem_raw[35840];
  bf16* const Ks = (bf16*)smem_raw;                // [64][KS_STRIDE]
  bf16* const Vt = (bf16*)(smem_raw + 17408);      // [128][VT_STRIDE]
  bf16* const Os = (bf16*)smem_raw;                // [128][KS_STRIDE] (output)

  const int tid  = threadIdx.x;
  const int wave = tid >> 6, lane = tid & 63;
  const int quad = lane >> 4, l16 = lane & 15;

  // T1: XCD swizzle over 512 blocks = 8 XCD x 64. XCD k<4 -> (b=0, kv=k);
  // k>=4 -> (b=1, kv=k-4): K+V working set 1MB per XCD, L2-resident.
  const int flat = blockIdx.x + 16 * blockIdx.y + 256 * blockIdx.z;
  const int swz  = (flat & 7) * 64 + (flat >> 3);
  const int qt = swz & 15, h = (swz >> 4) & 15, b = swz >> 8;

  const int kv = h >> 2;
  const int q0 = qt * 128;
  const int tok0 = b * S_LEN;
  const int qw = q0 + wave * 16;       // wave's first q-row
  const int q  = qw + l16;             // this thread's q-row

  bf16x8 qf[4];
  {
    const bf16* qp = Qg + (size_t)(tok0 + q) * (NH_Q * HD_) + h * HD_ + quad * 8;
#pragma unroll
    for (int kb = 0; kb < 4; ++kb) qf[kb] = *(const bf16x8*)(qp + kb * 32);
  }

  f32x4 o[8];
#pragma unroll
  for (int dt = 0; dt < 8; ++dt) o[dt] = (f32x4){0.f, 0.f, 0.f, 0.f};
  float m_run = -__builtin_inff(), l_run = 0.f;

  int kt_begin = q0 - WIN;
  if (kt_begin < 0) kt_begin = 0;
  const int kt_end = q0 + 128;
  const bf16* kg_base = Kg + (size_t)tok0 * (NH_KV * HD_) + kv * HD_;
  const bf16* vt_base = Vtg + (size_t)(b * NH_KV + kv) * HD_ * S_LEN;

  // staging thread constants (512 threads, 2 chunks each for K and V)
  const int skey = tid >> 4, sdbl = tid & 15;   // K: rows skey, skey+32
  const int svd  = tid >> 3, skb  = tid & 7;    // V: rows svd, svd+64

  bf16x8 pk0, pk1, pv0, pv1;  // T14 prefetch registers
  auto PF = [&](int kt) __attribute__((always_inline)) {
    pk0 = *(const bf16x8*)(kg_base + (size_t)(kt + skey) * (NH_KV * HD_) + sdbl * 8);
    pk1 = *(const bf16x8*)(kg_base + (size_t)(kt + skey + 32) * (NH_KV * HD_) + sdbl * 8);
    pv0 = *(const bf16x8*)(vt_base + (size_t)svd * S_LEN + kt + skb * 8);
    pv1 = *(const bf16x8*)(vt_base + (size_t)(svd + 64) * S_LEN + kt + skb * 8);
  };
  auto WR = [&]() __attribute__((always_inline)) {
    *(bf16x8*)&Ks[skey * KS_STRIDE + sdbl * 8] = pk0;
    *(bf16x8*)&Ks[(skey + 32) * KS_STRIDE + sdbl * 8] = pk1;
    *(bf16x8*)&Vt[svd * VT_STRIDE + skb * 8] = pv0;
    *(bf16x8*)&Vt[(svd + 64) * VT_STRIDE + skb * 8] = pv1;
  };

  PF(kt_begin);
  for (int kt = kt_begin; kt < kt_end; kt += 64) {
    __syncthreads();                 // previous tile's consumers done
    WR();                            // (compiler waits the PF loads)
    __syncthreads();
    if (kt + 64 < kt_end) PF(kt + 64);  // overlap next loads with compute

    // wave-uniform tile classification
    const bool active = (kt <= qw + 15) && (kt + 63 > qw - WIN);
    if (!active) continue;
    const bool need_c = (kt + 63 > qw);            // causal boundary tile
    const bool need_l = (kt + WIN <= qw + 15);     // lower-window boundary

    f32x4 st4[4];
    __builtin_amdgcn_s_setprio(1);
#pragma unroll
    for (int nt = 0; nt < 4; ++nt) {
      f32x4 acc = (f32x4){0.f, 0.f, 0.f, 0.f};
#pragma unroll
      for (int kb = 0; kb < 4; ++kb) {
        bf16x8 kf = *(const bf16x8*)&Ks[(nt * 16 + l16) * KS_STRIDE + kb * 32 + quad * 8];
        acc = __builtin_amdgcn_mfma_f32_16x16x32_bf16(kf, qf[kb], acc, 0, 0, 0);
      }
      st4[nt] = acc;
    }
    __builtin_amdgcn_s_setprio(0);

    if (need_c || need_l) {
#pragma unroll
      for (int nt = 0; nt < 4; ++nt)
#pragma unroll
        for (int r = 0; r < 4; ++r) {
          const int key = kt + nt * 16 + quad * 4 + r;
          const bool ok = (!need_c || key <= q) && (!need_l || key > q - WIN);
          st4[nt][r] = ok ? st4[nt][r] : -__builtin_inff();
        }
    }

    float mx = -__builtin_inff();
#pragma unroll
    for (int nt = 0; nt < 4; ++nt)
#pragma unroll
      for (int r = 0; r < 4; ++r) mx = fmaxf(mx, st4[nt][r]);
    mx = fmaxf(mx, __shfl_xor(mx, 16, 64));
    mx = fmaxf(mx, __shfl_xor(mx, 32, 64));

    // T13 defer-max: keep stale max unless some row grew by >8 (log2 units).
    float msub;
    if (!__all(mx - m_run <= 8.f)) {   // NaN(-inf - -inf) -> grow path
      const float mnew = fmaxf(m_run, mx);
      msub = (mnew == -__builtin_inff()) ? 0.f : mnew;
      const float alpha = __builtin_amdgcn_exp2f(m_run - msub);
      l_run *= alpha;
#pragma unroll
      for (int dt = 0; dt < 8; ++dt) o[dt] *= alpha;
      m_run = mnew;
    } else {
      msub = m_run;
    }

    float psum = 0.f;
    s16x4 pb[4];
#pragma unroll
    for (int nt = 0; nt < 4; ++nt)
#pragma unroll
      for (int r = 0; r < 4; ++r) {
        const float pv = __builtin_amdgcn_exp2f(st4[nt][r] - msub);
        psum += pv;
        union { __bf16 hh; short ss; } u;
        u.hh = (bf16)pv;
        pb[nt][r] = u.ss;
      }
    psum += __shfl_xor(psum, 16, 64);
    psum += __shfl_xor(psum, 32, 64);
    l_run += psum;

    __builtin_amdgcn_s_setprio(1);
#pragma unroll
    for (int dt = 0; dt < 8; ++dt)
#pragma unroll
      for (int nt = 0; nt < 4; ++nt) {
        s16x4 vf = *(const s16x4*)&Vt[(dt * 16 + l16) * VT_STRIDE + nt * 16 + quad * 4];
        o[dt] = __builtin_amdgcn_mfma_f32_16x16x16bf16_1k(vf, pb[nt], o[dt], 0, 0, 0);
      }
    __builtin_amdgcn_s_setprio(0);
  }

  const float inv = 1.f / l_run;
  __syncthreads();   // all LDS consumers done; reuse as output stage
#pragma unroll
  for (int dt = 0; dt < 8; ++dt) {
    bf16x4 t;
#pragma unroll
    for (int r = 0; r < 4; ++r) t[r] = (bf16)(o[dt][r] * inv);
    *(bf16x4*)&Os[(wave * 16 + l16) * KS_STRIDE + dt * 16 + quad * 4] = t;
  }
  __syncthreads();
#pragma unroll
  for (int it = 0; it < 4; ++it) {
    const int idx = tid + it * 512;
    const int row = idx >> 4, chunk = idx & 15;
    bf16x8 v = *(const bf16x8*)&Os[row * KS_STRIDE + chunk * 8];
    *(bf16x8*)(Og + (size_t)(tok0 + q0 + row) * (NH_Q * HD_) + h * HD_ + chunk * 8) = v;
  }
}

// ---------------- launcher ----------------
extern "C" void kernel_launch(void* const* d_in, const int* in_sizes, int n_in,
                              void* d_out, int out_size, void* d_ws, size_t ws_size,
                              hipStream_t stream) {
  const float* hs = (const float*)d_in[0];
  const float* Wq = (const float*)d_in[1];
  const float* Wk = (const float*)d_in[2];
  const float* Wv = (const float*)d_in[3];
  const float* Wo = (const float*)d_in[4];
  float* out = (float*)d_out;

  char* w = (char*)d_ws;
  bf16* hsb = (bf16*)w; w += (size_t)NTOK * 2048 * 2;   // 16.8 MB
  bf16* wqb = (bf16*)w; w += (size_t)2048 * 2048 * 2;   //  8.4 MB
  bf16* wkb = (bf16*)w; w += (size_t)512 * 2048 * 2;    //  2.1 MB
  bf16* wvb = (bf16*)w; w += (size_t)512 * 2048 * 2;    //  2.1 MB
  bf16* wob = (bf16*)w; w += (size_t)2048 * 2048 * 2;   //  8.4 MB
  bf16* qb  = (bf16*)w; w += (size_t)NTOK * 2048 * 2;   // 16.8 MB
  bf16* kb  = (bf16*)w; w += (size_t)NTOK * 512 * 2;    //  4.2 MB
  bf16* vtb = (bf16*)w; w += (size_t)NTOK * 512 * 2;    //  4.2 MB
  bf16* ab  = hsb;  // alias: hs_bf16 dead after QKV GEMM

  cvt_all<<<18874368 / 1024, 256, 0, stream>>>(hs, Wq, Wk, Wv, Wo,
                                               hsb, wqb, wkb, wvb, wob);

  gemm_qkv9<<<dim3(16, 16), 512, 0, stream>>>(hsb, wqb, wkb, wvb,
                                              qb, kb, vtb);

  attn_kernel<<<dim3(S_LEN / 128, NH_Q, 2), 512, 0, stream>>>(qb, kb, vtb, ab);

  gemm_out8<<<dim3(16, 16), 512, 0, stream>>>(ab, wob, out);
}

// Round 5
// 233.127 us; speedup vs baseline: 1.1889x; 1.0023x over previous
//
#include <hip/hip_runtime.h>
#include <cstdint>
#include <cstddef>

typedef __bf16 bf16;
typedef __attribute__((ext_vector_type(8))) __bf16 bf16x8;
typedef __attribute__((ext_vector_type(4))) __bf16 bf16x4;
typedef __attribute__((ext_vector_type(4))) float f32x4;
typedef __attribute__((ext_vector_type(4))) short s16x4;

#define S_LEN   2048
#define WIN     512
#define NH_Q    16
#define NH_KV   4
#define HD_     128
#define NTOK    4096   // B * S

// Q is pre-scaled by (1/sqrt(128)) * log2(e) at the QKV epilogue, so attn
// uses exp2 directly and needs no per-score scale multiply.
#define QSCALE_LOG2E 0.12751744561823337f

#if defined(__has_builtin)
#if __has_builtin(__builtin_amdgcn_mfma_f32_16x16x16bf16_1k)
#define HAVE_MFMA16 1
#endif
#endif
#ifndef HAVE_MFMA16
#define HAVE_MFMA16 0
#endif

// s_waitcnt immediates (gfx9 encoding: vm[3:0]=s[3:0], exp=s[6:4],
// lgkm=s[11:8], vm[5:4]=s[15:14]); non-waited fields all-ones.
#define WAIT_VM4   0x0F74  // vmcnt<=4
#define WAIT_VM3   0x0F73  // vmcnt<=3
#define WAIT_VM2   0x0F72  // vmcnt<=2
#define WAIT_VM0   0x0F70  // vmcnt<=0
#define WAIT_L0    0xC07F  // lgkmcnt<=0
#define WAIT_L4    0xC47F  // lgkmcnt<=4
#define WAIT_L6    0xC67F  // lgkmcnt<=6
#define WAIT_L10   0xCA7F  // lgkmcnt<=10
#define CFENCE() __asm__ __volatile__("" ::: "memory")

// async global->LDS, 16B per lane; LDS dest = wave-uniform base + lane*16
__device__ __forceinline__ void async_copy16(const void* g, void* l) {
  __builtin_amdgcn_global_load_lds(
      (const __attribute__((address_space(1))) void*)g,
      (__attribute__((address_space(3))) void*)l, 16, 0, 0);
}

// ---------------- fp32 -> bf16 convert, all 5 arrays in one launch ----------
__global__ __launch_bounds__(256)
void cvt_all(const float* __restrict__ hs, const float* __restrict__ wq,
             const float* __restrict__ wk, const float* __restrict__ wv,
             const float* __restrict__ wo, bf16* __restrict__ hsb,
             bf16* __restrict__ wqb, bf16* __restrict__ wkb,
             bf16* __restrict__ wvb, bf16* __restrict__ wob) {
  long i = ((long)blockIdx.x * 256 + threadIdx.x) * 4;  // < 18874368
  const float* in;
  bf16* out;
  if (i < 8388608)       { in = hs + i;            out = hsb + i; }
  else if (i < 12582912) { in = wq + (i - 8388608); out = wqb + (i - 8388608); }
  else if (i < 13631488) { in = wk + (i - 12582912); out = wkb + (i - 12582912); }
  else if (i < 14680064) { in = wv + (i - 13631488); out = wvb + (i - 13631488); }
  else                   { in = wo + (i - 14680064); out = wob + (i - 14680064); }
  float4 v = *(const float4*)in;
  bf16x4 t = {(bf16)v.x, (bf16)v.y, (bf16)v.z, (bf16)v.w};
  *(bf16x4*)out = t;
}

// ---------------- output GEMM: 256x128 tile, 4-phase schedule, 1 block/CU ---
__global__ __launch_bounds__(512, 2)
void gemm_out8(const bf16* __restrict__ A, const bf16* __restrict__ W,
               float* __restrict__ C) {
  __shared__ __align__(16) char smem[98304];  // A[2]: 0/32K, B[2]: 64K/80K
  const int tid  = threadIdx.x;
  const int wave = tid >> 6, lane = tid & 63;
  const int quad = lane >> 4, l16 = lane & 15;
  const int wm = wave >> 1, wn = wave & 1;   // 4x2 wave grid, 64x64 each

  // XCD-swizzled tile coords (grid 16(n) x 16(m) = 256 = 8 XCD x 32)
  const int flat = blockIdx.y * 16 + blockIdx.x;
  const int swz  = (flat & 7) * 32 + (flat >> 3);
  const int m0 = (swz >> 4) * 256;
  const int n0 = (swz & 15) * 128;

  // swizzled within-subtile read byte offset (st_16x32, R6-verified)
  const int rdb = (l16 * 64 + quad * 16) ^ ((l16 & 8) << 2);
  const int srow = lane >> 2;
  const int scol = ((lane & 3) * 8) ^ ((lane >> 5) << 4);

  const bf16* aptr[2][2];
  int adst[2][2];
#pragma unroll
  for (int mh = 0; mh < 2; ++mh)
#pragma unroll
    for (int j = 0; j < 2; ++j) {
      const int rb = (wave >> 1) * 4 + mh * 2 + j;
      aptr[mh][j] = A + (size_t)(m0 + rb * 16 + srow) * 2048 + scol
                    + (wave & 1) * 32;
      adst[mh][j] = (rb * 2 + (wave & 1)) << 10;
    }
  const bf16* bptr[2];
  int bdst[2];
#pragma unroll
  for (int nh = 0; nh < 2; ++nh) {
    const int cb = (wave >> 2) * 4 + nh * 2 + ((wave >> 1) & 1);
    bptr[nh] = W + (size_t)(n0 + cb * 16 + srow) * 2048 + scol
               + (wave & 1) * 32;
    bdst[nh] = (cb * 2 + (wave & 1)) << 10;
  }

#define STAGE_A(mh, tt) do { char* _b = smem + ((tt) & 1) * 32768;      \
    async_copy16(aptr[mh][0] + (tt) * 64, _b + adst[mh][0]);            \
    async_copy16(aptr[mh][1] + (tt) * 64, _b + adst[mh][1]); } while (0)
#define STAGE_B(nh, tt) do { char* _b = smem + 65536 + ((tt) & 1) * 16384; \
    async_copy16(bptr[nh] + (tt) * 64, _b + bdst[nh]); } while (0)

  f32x4 acc[4][4];
#pragma unroll
  for (int i = 0; i < 4; ++i)
#pragma unroll
    for (int j = 0; j < 4; ++j) acc[i][j] = (f32x4){0.f, 0.f, 0.f, 0.f};

  bf16x8 afr[2][2];
  bf16x8 bfr[2][2][2];

  auto read_a = [&](const char* Ab, int mh) __attribute__((always_inline)) {
#pragma unroll
    for (int mt2 = 0; mt2 < 2; ++mt2)
#pragma unroll
      for (int ks = 0; ks < 2; ++ks)
        afr[mt2][ks] = *(const bf16x8*)(
            Ab + (((wm * 4 + mh * 2 + mt2) * 2 + ks) << 10) + rdb);
  };
  auto read_b = [&](const char* Bb, int nh) __attribute__((always_inline)) {
#pragma unroll
    for (int nt2 = 0; nt2 < 2; ++nt2)
#pragma unroll
      for (int ks = 0; ks < 2; ++ks)
        bfr[nh][nt2][ks] = *(const bf16x8*)(
            Bb + (((wn * 4 + nh * 2 + nt2) * 2 + ks) << 10) + rdb);
  };
  auto do_mfma = [&](int mh, int nh) __attribute__((always_inline)) {
    __builtin_amdgcn_s_setprio(1);
#pragma unroll
    for (int mt2 = 0; mt2 < 2; ++mt2)
#pragma unroll
      for (int nt2 = 0; nt2 < 2; ++nt2)
#pragma unroll
        for (int ks = 0; ks < 2; ++ks)
          acc[mh * 2 + mt2][nh * 2 + nt2] = __builtin_amdgcn_mfma_f32_16x16x32_bf16(
              afr[mt2][ks], bfr[nh][nt2][ks], acc[mh * 2 + mt2][nh * 2 + nt2],
              0, 0, 0);
    __builtin_amdgcn_s_setprio(0);
  };

  STAGE_A(0, 0); STAGE_B(0, 0); STAGE_B(1, 0); STAGE_A(1, 0);
  CFENCE();

  for (int t = 0; t < 31; ++t) {
    const char* Ab = smem + (t & 1) * 32768;
    const char* Bb = smem + 65536 + (t & 1) * 16384;
    const int nx = t + 1;
    __builtin_amdgcn_s_waitcnt(WAIT_VM3); CFENCE();
    __builtin_amdgcn_s_barrier(); CFENCE();
    read_a(Ab, 0); read_b(Bb, 0);
    STAGE_A(0, nx); CFENCE();
    do_mfma(0, 0);
    __builtin_amdgcn_s_waitcnt(WAIT_VM4); CFENCE();
    __builtin_amdgcn_s_barrier(); CFENCE();
    read_b(Bb, 1);
    STAGE_B(0, nx); CFENCE();
    do_mfma(0, 1);
    __builtin_amdgcn_s_waitcnt(WAIT_VM3); CFENCE();
    __builtin_amdgcn_s_barrier(); CFENCE();
    read_a(Ab, 1);
    STAGE_B(1, nx); CFENCE();
    do_mfma(1, 0);
    __builtin_amdgcn_s_barrier(); CFENCE();
    STAGE_A(1, nx); CFENCE();
    do_mfma(1, 1);
  }
  {
    const char* Ab = smem + 32768;
    const char* Bb = smem + 65536 + 16384;
    __builtin_amdgcn_s_waitcnt(WAIT_VM3); CFENCE();
    __builtin_amdgcn_s_barrier(); CFENCE();
    read_a(Ab, 0); read_b(Bb, 0);
    do_mfma(0, 0);
    __builtin_amdgcn_s_waitcnt(WAIT_VM2); CFENCE();
    __builtin_amdgcn_s_barrier(); CFENCE();
    read_b(Bb, 1);
    do_mfma(0, 1);
    __builtin_amdgcn_s_waitcnt(WAIT_VM0); CFENCE();
    __builtin_amdgcn_s_barrier(); CFENCE();
    read_a(Ab, 1);
    do_mfma(1, 0);
    do_mfma(1, 1);
  }
#undef STAGE_A
#undef STAGE_B

#pragma unroll
  for (int mt = 0; mt < 4; ++mt)
#pragma unroll
    for (int nt = 0; nt < 4; ++nt)
#pragma unroll
      for (int r = 0; r < 4; ++r) {
        const int row = m0 + wm * 64 + mt * 16 + quad * 4 + r;
        const int col = n0 + wn * 64 + nt * 16 + l16;
        C[(size_t)row * 2048 + col] = acc[mt][nt][r];
      }
}

// ---------------- fused QKV GEMM v10: pipelined uniform 12-MFMA phases ------
// R4 counters (qkv9): 52.9us, MfmaUtil 35.9, VALUBusy 19.5 -> 44% stall.
// Cause: read-then-use phases (barrier -> ds_read -> ~120cy -> MFMA) with
// imbalanced 8/16/8/16 MFMA and only 2 waves/SIMD. Fix (m201 pattern): phases
// split by (mh, ks) = uniform 12 MFMA; each phase's frags are ds_read ONE
// PHASE EARLY; MFMA entry waits a COUNTED lgkmcnt(N = reads just issued) +
// sched_barrier (rule 18). vmcnt ledger (stages: Ph1 A0'(2), Ph2 B'(3),
// Ph3 A1'(2)): Ph2 entry in-flight [A1(t)2, A0'(2)] -> vm2 retires A1(t);
// Ph4 entry [A0'2, B'3, A1'2] -> vm2 retires A0'+B' (exactly what Ph4
// reads). Never vm0 in main loop. Cross-tile LDS reads (Ph4) sit behind
// barrier4 which follows every wave's own vm2 -> collective confirmation.
__global__ __launch_bounds__(512, 2)
void gemm_qkv10(const bf16* __restrict__ A, const bf16* __restrict__ Wq,
                const bf16* __restrict__ Wk, const bf16* __restrict__ Wv,
                bf16* __restrict__ Qo, bf16* __restrict__ Ko,
                bf16* __restrict__ Vt) {
  __shared__ __align__(16) char smem[114688];  // A[2]: 0/32K, B[2]: 64K/88K
  const int tid  = threadIdx.x;
  const int wave = tid >> 6, lane = tid & 63;
  const int quad = lane >> 4, l16 = lane & 15;
  const int wm = wave >> 1, wn = wave & 1;   // 4x2 wave grid, 64 rows x 96 cols

  const int flat = blockIdx.y * 16 + blockIdx.x;
  const int swz  = (flat & 7) * 32 + (flat >> 3);
  const int m0 = (swz >> 4) * 256;
  const int n0 = (swz & 15) * 192;

  const int rdb = (l16 * 64 + quad * 16) ^ ((l16 & 8) << 2);
  const int srow = lane >> 2;
  const int scol = ((lane & 3) * 8) ^ ((lane >> 5) << 4);

  const int rbA0 = (wave >> 1) * 4 + (wave & 1);
  const int rbA1 = rbA0 + 2;
  const bf16* a0p = A + (size_t)(m0 + rbA0 * 16 + srow) * 2048 + scol;
  const bf16* a1p = A + (size_t)(m0 + rbA1 * 16 + srow) * 2048 + scol;
  const int da0 = (rbA0 * 2) << 10;
  const int da1 = (rbA1 * 2) << 10;

  const int rbB0 = wave >> 1, khB0 = wave & 1;
  const int rbB1 = 4 + wave;
  const int nrow0 = n0 + rbB0 * 16 + srow;
  const int nrow1 = n0 + rbB1 * 16 + srow;
  const bf16* b0p = (nrow0 < 2048 ? Wq + (size_t)nrow0 * 2048
                   : nrow0 < 2560 ? Wk + (size_t)(nrow0 - 2048) * 2048
                                  : Wv + (size_t)(nrow0 - 2560) * 2048)
                    + scol + khB0 * 32;
  const bf16* b1p = (nrow1 < 2048 ? Wq + (size_t)nrow1 * 2048
                   : nrow1 < 2560 ? Wk + (size_t)(nrow1 - 2048) * 2048
                                  : Wv + (size_t)(nrow1 - 2560) * 2048)
                    + scol;
  const int db0 = (rbB0 * 2 + khB0) << 10;
  const int db1 = (rbB1 * 2) << 10;

#define STAGE_A0(tt) do { char* _b = smem + ((tt) & 1) * 32768;        \
    async_copy16(a0p + (tt) * 64,      _b + da0);                      \
    async_copy16(a0p + (tt) * 64 + 32, _b + da0 + 1024); } while (0)
#define STAGE_A1(tt) do { char* _b = smem + ((tt) & 1) * 32768;        \
    async_copy16(a1p + (tt) * 64,      _b + da1);                      \
    async_copy16(a1p + (tt) * 64 + 32, _b + da1 + 1024); } while (0)
#define STAGE_B0(tt) do { char* _b = smem + 65536 + ((tt) & 1) * 24576; \
    async_copy16(b0p + (tt) * 64,      _b + db0); } while (0)
#define STAGE_B12(tt) do { char* _b = smem + 65536 + ((tt) & 1) * 24576; \
    async_copy16(b1p + (tt) * 64,      _b + db1);                      \
    async_copy16(b1p + (tt) * 64 + 32, _b + db1 + 1024); } while (0)

  f32x4 acc[4][6];
#pragma unroll
  for (int i = 0; i < 4; ++i)
#pragma unroll
    for (int j = 0; j < 6; ++j) acc[i][j] = (f32x4){0.f, 0.f, 0.f, 0.f};

  bf16x8 afr0[2][2];   // A0 frags (rows wm*64 + 0..31), both k-slices
  bf16x8 afr1[2][2];   // A1 frags (rows wm*64 + 32..63)
  bf16x8 bfr[6][2];    // all 6 interleaved n-chunks x 2 k-slices

  auto read_a0 = [&](const char* Ab) __attribute__((always_inline)) {
#pragma unroll
    for (int mt2 = 0; mt2 < 2; ++mt2)
#pragma unroll
      for (int ks = 0; ks < 2; ++ks)
        afr0[mt2][ks] = *(const bf16x8*)(
            Ab + (((wm * 4 + mt2) * 2 + ks) << 10) + rdb);
  };
  auto read_a1 = [&](const char* Ab) __attribute__((always_inline)) {
#pragma unroll
    for (int mt2 = 0; mt2 < 2; ++mt2)
#pragma unroll
      for (int ks = 0; ks < 2; ++ks)
        afr1[mt2][ks] = *(const bf16x8*)(
            Ab + (((wm * 4 + 2 + mt2) * 2 + ks) << 10) + rdb);
  };
  auto read_b_ks = [&](const char* Bb, int ks) __attribute__((always_inline)) {
#pragma unroll
    for (int j = 0; j < 6; ++j) {
      const int cc = (j >> 1) * 4 + (j & 1) * 2 + wn;
      bfr[j][ks] = *(const bf16x8*)(Bb + ((cc * 2 + ks) << 10) + rdb);
    }
  };
  auto mfma0 = [&](int ks) __attribute__((always_inline)) {   // acc rows 0,1
    __builtin_amdgcn_s_setprio(1);
#pragma unroll
    for (int mt2 = 0; mt2 < 2; ++mt2)
#pragma unroll
      for (int j = 0; j < 6; ++j)
        acc[mt2][j] = __builtin_amdgcn_mfma_f32_16x16x32_bf16(
            afr0[mt2][ks], bfr[j][ks], acc[mt2][j], 0, 0, 0);
    __builtin_amdgcn_s_setprio(0);
  };
  auto mfma1 = [&](int ks) __attribute__((always_inline)) {   // acc rows 2,3
    __builtin_amdgcn_s_setprio(1);
#pragma unroll
    for (int mt2 = 0; mt2 < 2; ++mt2)
#pragma unroll
      for (int j = 0; j < 6; ++j)
        acc[2 + mt2][j] = __builtin_amdgcn_mfma_f32_16x16x32_bf16(
            afr1[mt2][ks], bfr[j][ks], acc[2 + mt2][j], 0, 0, 0);
    __builtin_amdgcn_s_setprio(0);
  };

  // prologue: stage tile 0, drain once (prologue-only vm0), preload phase-1
  // frags (A0 + B ks0 of tile 0).
  STAGE_A0(0); STAGE_B0(0); STAGE_B12(0); STAGE_A1(0);
  CFENCE();
  __builtin_amdgcn_s_waitcnt(WAIT_VM0); CFENCE();
  __builtin_amdgcn_s_barrier(); CFENCE();
  read_a0(smem);
  read_b_ks(smem + 65536, 0);
  CFENCE();

  for (int t = 0; t < 31; ++t) {
    const char* Ab  = smem + (t & 1) * 32768;
    const char* Bb  = smem + 65536 + (t & 1) * 24576;
    const char* Abn = smem + ((t + 1) & 1) * 32768;
    const char* Bbn = smem + 65536 + ((t + 1) & 1) * 24576;
    const int nx = t + 1;
    // Ph1: MFMA(A0,ks0); read B ks1; stage A0'
    __builtin_amdgcn_s_barrier(); CFENCE();
    read_b_ks(Bb, 1);
    STAGE_A0(nx); CFENCE();
    __builtin_amdgcn_s_waitcnt(WAIT_L6);
    __builtin_amdgcn_sched_barrier(0);
    mfma0(0);
    // Ph2: MFMA(A0,ks1); read A1; stage B'
    __builtin_amdgcn_s_waitcnt(WAIT_VM2); CFENCE();
    __builtin_amdgcn_s_barrier(); CFENCE();
    read_a1(Ab);
    STAGE_B0(nx); STAGE_B12(nx); CFENCE();
    __builtin_amdgcn_s_waitcnt(WAIT_L4);
    __builtin_amdgcn_sched_barrier(0);
    mfma0(1);
    // Ph3: MFMA(A1,ks0); stage A1'
    __builtin_amdgcn_s_barrier(); CFENCE();
    STAGE_A1(nx); CFENCE();
    __builtin_amdgcn_s_waitcnt(WAIT_L0);
    __builtin_amdgcn_sched_barrier(0);
    mfma1(0);
    // Ph4: MFMA(A1,ks1); read next-tile A0 + B ks0
    __builtin_amdgcn_s_waitcnt(WAIT_VM2); CFENCE();
    __builtin_amdgcn_s_barrier(); CFENCE();
    read_a0(Abn);
    read_b_ks(Bbn, 0);
    CFENCE();
    __builtin_amdgcn_s_waitcnt(WAIT_L10);
    __builtin_amdgcn_sched_barrier(0);
    mfma1(1);
  }
  {  // peeled last tile (t=31, buf1): drain A1(31) at Ph2
    const char* Ab = smem + 32768;
    const char* Bb = smem + 65536 + 24576;
    __builtin_amdgcn_s_barrier(); CFENCE();
    read_b_ks(Bb, 1); CFENCE();
    __builtin_amdgcn_s_waitcnt(WAIT_L6);
    __builtin_amdgcn_sched_barrier(0);
    mfma0(0);
    __builtin_amdgcn_s_waitcnt(WAIT_VM0); CFENCE();
    __builtin_amdgcn_s_barrier(); CFENCE();
    read_a1(Ab); CFENCE();
    __builtin_amdgcn_s_waitcnt(WAIT_L4);
    __builtin_amdgcn_sched_barrier(0);
    mfma0(1);
    __builtin_amdgcn_s_waitcnt(WAIT_L0);
    __builtin_amdgcn_sched_barrier(0);
    mfma1(0);
    mfma1(1);
  }
#undef STAGE_A0
#undef STAGE_A1
#undef STAGE_B0
#undef STAGE_B12

  // epilogue: RoPE on rotary 64-blocks (cb ≡ 0 mod 128, cb < 2560).
  {
    const float d = (float)(wn * 16 + l16);
    const float invf = exp2f(-d * 0.41524101186091903f);  // 1e4^(-d/32)
#pragma unroll
    for (int b = 0; b < 3; ++b) {
      const int cb = n0 + b * 64;
      if (cb < 2560 && (cb & 127) == 0) {
#pragma unroll
        for (int mt = 0; mt < 4; ++mt)
#pragma unroll
          for (int r = 0; r < 4; ++r) {
            const int pos = (m0 + wm * 64 + mt * 16 + quad * 4 + r) & (S_LEN - 1);
            float s, c;
            __sincosf((float)pos * invf, &s, &c);
            const float x1 = acc[mt][2 * b][r], x2 = acc[mt][2 * b + 1][r];
            acc[mt][2 * b][r]     = x1 * c - x2 * s;
            acc[mt][2 * b + 1][r] = x2 * c + x1 * s;
          }
      }
    }
  }
#pragma unroll
  for (int mt = 0; mt < 4; ++mt) {
    const int row0 = m0 + wm * 64 + mt * 16 + quad * 4;
#pragma unroll
    for (int j = 0; j < 6; ++j) {
      const int col16 = n0 + (j >> 1) * 64 + ((j & 1) * 2 + wn) * 16;
      if (col16 < 2048) {                 // Q: [tok][2048], pre-scaled
#pragma unroll
        for (int r = 0; r < 4; ++r)
          Qo[(size_t)(row0 + r) * 2048 + col16 + l16] =
              (bf16)(acc[mt][j][r] * QSCALE_LOG2E);
      } else if (col16 < 2560) {          // K: [tok][512]
#pragma unroll
        for (int r = 0; r < 4; ++r)
          Ko[(size_t)(row0 + r) * 512 + col16 - 2048 + l16] = (bf16)acc[mt][j][r];
      } else {                            // V: transposed vt[(b*4+kv)*128+d][s]
        const int colv = col16 + l16 - 2560;
        const int bb = row0 >> 11, s0 = row0 & (S_LEN - 1);
        bf16x4 tq = {(bf16)acc[mt][j][0], (bf16)acc[mt][j][1],
                     (bf16)acc[mt][j][2], (bf16)acc[mt][j][3]};
        *(bf16x4*)(Vt + ((size_t)(bb * NH_KV + (colv >> 7)) * HD_ + (colv & 127))
                        * S_LEN + s0) = tq;
      }
    }
  }
}

// ---------------- flash attention v2: 128-query blocks, 8 waves -------------
#define KS_STRIDE 136   // 64 keys x 128 d (+pad)
#define VT_STRIDE 72    // 128 d x 64 keys (+pad)

__global__ __launch_bounds__(512, 4)
void attn_kernel(const bf16* __restrict__ Qg, const bf16* __restrict__ Kg,
                 const bf16* __restrict__ Vtg, bf16* __restrict__ Og) {
  __shared__ __align__(16) char smem_raw[35840];
  bf16* const Ks = (bf16*)smem_raw;                // [64][KS_STRIDE]
  bf16* const Vt = (bf16*)(smem_raw + 17408);      // [128][VT_STRIDE]
  bf16* const Os = (bf16*)smem_raw;                // [128][KS_STRIDE] (output)

  const int tid  = threadIdx.x;
  const int wave = tid >> 6, lane = tid & 63;
  const int quad = lane >> 4, l16 = lane & 15;

  // T1: XCD swizzle over 512 blocks = 8 XCD x 64.
  const int flat = blockIdx.x + 16 * blockIdx.y + 256 * blockIdx.z;
  const int swz  = (flat & 7) * 64 + (flat >> 3);
  const int qt = swz & 15, h = (swz >> 4) & 15, b = swz >> 8;

  const int kv = h >> 2;
  const int q0 = qt * 128;
  const int tok0 = b * S_LEN;
  const int qw = q0 + wave * 16;       // wave's first q-row
  const int q  = qw + l16;             // this thread's q-row

  bf16x8 qf[4];
  {
    const bf16* qp = Qg + (size_t)(tok0 + q) * (NH_Q * HD_) + h * HD_ + quad * 8;
#pragma unroll
    for (int kb = 0; kb < 4; ++kb) qf[kb] = *(const bf16x8*)(qp + kb * 32);
  }

  f32x4 o[8];
#pragma unroll
  for (int dt = 0; dt < 8; ++dt) o[dt] = (f32x4){0.f, 0.f, 0.f, 0.f};
  float m_run = -__builtin_inff(), l_run = 0.f;

  int kt_begin = q0 - WIN;
  if (kt_begin < 0) kt_begin = 0;
  const int kt_end = q0 + 128;
  const bf16* kg_base = Kg + (size_t)tok0 * (NH_KV * HD_) + kv * HD_;
  const bf16* vt_base = Vtg + (size_t)(b * NH_KV + kv) * HD_ * S_LEN;

  // staging thread constants (512 threads, 2 chunks each for K and V)
  const int skey = tid >> 4, sdbl = tid & 15;   // K: rows skey, skey+32
  const int svd  = tid >> 3, skb  = tid & 7;    // V: rows svd, svd+64

  bf16x8 pk0, pk1, pv0, pv1;  // T14 prefetch registers
  auto PF = [&](int kt) __attribute__((always_inline)) {
    pk0 = *(const bf16x8*)(kg_base + (size_t)(kt + skey) * (NH_KV * HD_) + sdbl * 8);
    pk1 = *(const bf16x8*)(kg_base + (size_t)(kt + skey + 32) * (NH_KV * HD_) + sdbl * 8);
    pv0 = *(const bf16x8*)(vt_base + (size_t)svd * S_LEN + kt + skb * 8);
    pv1 = *(const bf16x8*)(vt_base + (size_t)(svd + 64) * S_LEN + kt + skb * 8);
  };
  auto WR = [&]() __attribute__((always_inline)) {
    *(bf16x8*)&Ks[skey * KS_STRIDE + sdbl * 8] = pk0;
    *(bf16x8*)&Ks[(skey + 32) * KS_STRIDE + sdbl * 8] = pk1;
    *(bf16x8*)&Vt[svd * VT_STRIDE + skb * 8] = pv0;
    *(bf16x8*)&Vt[(svd + 64) * VT_STRIDE + skb * 8] = pv1;
  };

  PF(kt_begin);
  for (int kt = kt_begin; kt < kt_end; kt += 64) {
    __syncthreads();                 // previous tile's consumers done
    WR();                            // (compiler waits the PF loads)
    __syncthreads();
    if (kt + 64 < kt_end) PF(kt + 64);  // overlap next loads with compute

    // wave-uniform tile classification
    const bool active = (kt <= qw + 15) && (kt + 63 > qw - WIN);
    if (!active) continue;
    const bool need_c = (kt + 63 > qw);            // causal boundary tile
    const bool need_l = (kt + WIN <= qw + 15);     // lower-window boundary

    f32x4 st4[4];
    __builtin_amdgcn_s_setprio(1);
#pragma unroll
    for (int nt = 0; nt < 4; ++nt) {
      f32x4 acc = (f32x4){0.f, 0.f, 0.f, 0.f};
#pragma unroll
      for (int kb = 0; kb < 4; ++kb) {
        bf16x8 kf = *(const bf16x8*)&Ks[(nt * 16 + l16) * KS_STRIDE + kb * 32 + quad * 8];
        acc = __builtin_amdgcn_mfma_f32_16x16x32_bf16(kf, qf[kb], acc, 0, 0, 0);
      }
      st4[nt] = acc;
    }
    __builtin_amdgcn_s_setprio(0);

    if (need_c || need_l) {
#pragma unroll
      for (int nt = 0; nt < 4; ++nt)
#pragma unroll
        for (int r = 0; r < 4; ++r) {
          const int key = kt + nt * 16 + quad * 4 + r;
          const bool ok = (!need_c || key <= q) && (!need_l || key > q - WIN);
          st4[nt][r] = ok ? st4[nt][r] : -__builtin_inff();
        }
    }

    float mx = -__builtin_inff();
#pragma unroll
    for (int nt = 0; nt < 4; ++nt)
#pragma unroll
      for (int r = 0; r < 4; ++r) mx = fmaxf(mx, st4[nt][r]);
    mx = fmaxf(mx, __shfl_xor(mx, 16, 64));
    mx = fmaxf(mx, __shfl_xor(mx, 32, 64));

    // T13 defer-max: keep stale max unless some row grew by >8 (log2 units).
    float msub;
    if (!__all(mx - m_run <= 8.f)) {   // NaN(-inf - -inf) -> grow path
      const float mnew = fmaxf(m_run, mx);
      msub = (mnew == -__builtin_inff()) ? 0.f : mnew;
      const float alpha = __builtin_amdgcn_exp2f(m_run - msub);
      l_run *= alpha;
#pragma unroll
      for (int dt = 0; dt < 8; ++dt) o[dt] *= alpha;
      m_run = mnew;
    } else {
      msub = m_run;
    }

    float psum = 0.f;
    s16x4 pb[4];
#pragma unroll
    for (int nt = 0; nt < 4; ++nt)
#pragma unroll
      for (int r = 0; r < 4; ++r) {
        const float pv = __builtin_amdgcn_exp2f(st4[nt][r] - msub);
        psum += pv;
        union { __bf16 hh; short ss; } u;
        u.hh = (bf16)pv;
        pb[nt][r] = u.ss;
      }
    psum += __shfl_xor(psum, 16, 64);
    psum += __shfl_xor(psum, 32, 64);
    l_run += psum;

    __builtin_amdgcn_s_setprio(1);
#pragma unroll
    for (int dt = 0; dt < 8; ++dt)
#pragma unroll
      for (int nt = 0; nt < 4; ++nt) {
        s16x4 vf = *(const s16x4*)&Vt[(dt * 16 + l16) * VT_STRIDE + nt * 16 + quad * 4];
        o[dt] = __builtin_amdgcn_mfma_f32_16x16x16bf16_1k(vf, pb[nt], o[dt], 0, 0, 0);
      }
    __builtin_amdgcn_s_setprio(0);
  }

  const float inv = 1.f / l_run;
  __syncthreads();   // all LDS consumers done; reuse as output stage
#pragma unroll
  for (int dt = 0; dt < 8; ++dt) {
    bf16x4 t;
#pragma unroll
    for (int r = 0; r < 4; ++r) t[r] = (bf16)(o[dt][r] * inv);
    *(bf16x4*)&Os[(wave * 16 + l16) * KS_STRIDE + dt * 16 + quad * 4] = t;
  }
  __syncthreads();
#pragma unroll
  for (int it = 0; it < 4; ++it) {
    const int idx = tid + it * 512;
    const int row = idx >> 4, chunk = idx & 15;
    bf16x8 v = *(const bf16x8*)&Os[row * KS_STRIDE + chunk * 8];
    *(bf16x8*)(Og + (size_t)(tok0 + q0 + row) * (NH_Q * HD_) + h * HD_ + chunk * 8) = v;
  }
}

// ---------------- launcher ----------------
extern "C" void kernel_launch(void* const* d_in, const int* in_sizes, int n_in,
                              void* d_out, int out_size, void* d_ws, size_t ws_size,
                              hipStream_t stream) {
  const float* hs = (const float*)d_in[0];
  const float* Wq = (const float*)d_in[1];
  const float* Wk = (const float*)d_in[2];
  const float* Wv = (const float*)d_in[3];
  const float* Wo = (const float*)d_in[4];
  float* out = (float*)d_out;

  char* w = (char*)d_ws;
  bf16* hsb = (bf16*)w; w += (size_t)NTOK * 2048 * 2;   // 16.8 MB
  bf16* wqb = (bf16*)w; w += (size_t)2048 * 2048 * 2;   //  8.4 MB
  bf16* wkb = (bf16*)w; w += (size_t)512 * 2048 * 2;    //  2.1 MB
  bf16* wvb = (bf16*)w; w += (size_t)512 * 2048 * 2;    //  2.1 MB
  bf16* wob = (bf16*)w; w += (size_t)2048 * 2048 * 2;   //  8.4 MB
  bf16* qb  = (bf16*)w; w += (size_t)NTOK * 2048 * 2;   // 16.8 MB
  bf16* kb  = (bf16*)w; w += (size_t)NTOK * 512 * 2;    //  4.2 MB
  bf16* vtb = (bf16*)w; w += (size_t)NTOK * 512 * 2;    //  4.2 MB
  bf16* ab  = hsb;  // alias: hs_bf16 dead after QKV GEMM

  cvt_all<<<18874368 / 1024, 256, 0, stream>>>(hs, Wq, Wk, Wv, Wo,
                                               hsb, wqb, wkb, wvb, wob);

  gemm_qkv10<<<dim3(16, 16), 512, 0, stream>>>(hsb, wqb, wkb, wvb,
                                               qb, kb, vtb);

  attn_kernel<<<dim3(S_LEN / 128, NH_Q, 2), 512, 0, stream>>>(qb, kb, vtb, ab);

  gemm_out8<<<dim3(16, 16), 512, 0, stream>>>(ab, wob, out);
}